// Round 1
// baseline (616.258 us; speedup 1.0000x reference)
//
#include <hip/hip_runtime.h>
#include <math.h>

// ---- problem constants (match reference) ----
#define NNODES 100000
#define NEDGES 1600000
#define NLABEL 100000
#define DIM    64
#define ALPHA  0.25f            // 1/(NUM_LAYERS+1)
#define NCHUNK ((NNODES + 1023) / 1024)   // 98

// ---- workspace layout (in 4-byte elements, 128-elem aligned) ----
// total = 21201152 elems * 4B ~= 80.9 MiB
constexpr size_t OFF_DEG    = 0;         // int  [100000]
constexpr size_t OFF_DIS    = 100096;    // f32  [100000]
constexpr size_t OFF_ROWPTR = 200192;    // int  [100001]
constexpr size_t OFF_CURSOR = 300288;    // int  [100000]
constexpr size_t OFF_CSUM   = 400384;    // int  [128]
constexpr size_t OFF_COFF   = 400512;    // int  [128]
constexpr size_t OFF_COL    = 400640;    // int  [1600000]
constexpr size_t OFF_BUFA   = 2000640;   // f32  [6400000]
constexpr size_t OFF_BUFB   = 8400640;   // f32  [6400000]
constexpr size_t OFF_OUT    = 14800640;  // f32  [6400000]
constexpr size_t OFF_PART   = 21200640;  // f32  [512]

__global__ void k_zero_deg(int* __restrict__ deg) {
    int i = blockIdx.x * blockDim.x + threadIdx.x;
    if (i < NNODES) deg[i] = 0;
}

__global__ void k_hist(const int* __restrict__ ei, int* __restrict__ deg) {
    int e = blockIdx.x * blockDim.x + threadIdx.x;
    if (e < NEDGES) atomicAdd(&deg[ei[NEDGES + e]], 1);
}

__global__ void k_dis(const int* __restrict__ deg, float* __restrict__ dis) {
    int i = blockIdx.x * blockDim.x + threadIdx.x;
    if (i < NNODES) {
        int d = deg[i];
        dis[i] = (d > 0) ? rsqrtf((float)d) : 0.0f;
    }
}

// exclusive scan of deg -> rowptr (within 1024-chunks) + per-chunk totals
__global__ void k_scan1(const int* __restrict__ deg, int* __restrict__ rowptr,
                        int* __restrict__ csum) {
    __shared__ int s[1024];
    int tid = threadIdx.x;
    int i = blockIdx.x * 1024 + tid;
    int v = (i < NNODES) ? deg[i] : 0;
    s[tid] = v;
    __syncthreads();
    for (int off = 1; off < 1024; off <<= 1) {
        int t = s[tid];
        if (tid >= off) t += s[tid - off];
        __syncthreads();
        s[tid] = t;
        __syncthreads();
    }
    int incl = s[tid];
    if (i < NNODES) rowptr[i] = incl - v;     // exclusive within chunk
    if (tid == 1023) csum[blockIdx.x] = incl; // chunk total
}

// exclusive scan of the (<=128) chunk totals
__global__ void k_scan2(const int* __restrict__ csum, int* __restrict__ coff) {
    __shared__ int s[128];
    int tid = threadIdx.x;
    int v = (tid < NCHUNK) ? csum[tid] : 0;
    s[tid] = v;
    __syncthreads();
    for (int off = 1; off < 128; off <<= 1) {
        int t = s[tid];
        if (tid >= off) t += s[tid - off];
        __syncthreads();
        s[tid] = t;
        __syncthreads();
    }
    if (tid < NCHUNK) coff[tid] = s[tid] - v;
}

// add chunk offsets; copy to cursor; close rowptr
__global__ void k_scan3(int* __restrict__ rowptr, const int* __restrict__ coff,
                        int* __restrict__ cursor) {
    int i = blockIdx.x * blockDim.x + threadIdx.x;
    if (i < NNODES) {
        int rp = rowptr[i] + coff[i >> 10];
        rowptr[i] = rp;
        cursor[i] = rp;
    }
    if (i == NNODES) rowptr[NNODES] = NEDGES;
}

__global__ void k_fill(const int* __restrict__ ei, int* __restrict__ cursor,
                       int* __restrict__ col) {
    int e = blockIdx.x * blockDim.x + threadIdx.x;
    if (e < NEDGES) {
        int s = ei[e];
        int d = ei[NEDGES + e];
        int pos = atomicAdd(&cursor[d], 1);
        col[pos] = s;
    }
}

// one wave per node, lane = embedding dim.
// x_next[i] = dis[i] * sum_{j in row(i)} dis[col_j] * x[col_j]
// out accumulation fused: FIRST -> out = ALPHA*(emb + y); else out += ALPHA*y
template <int FIRST>
__global__ __launch_bounds__(256) void k_prop(
    const int* __restrict__ rowptr, const int* __restrict__ col,
    const float* __restrict__ dis, const float* __restrict__ xin,
    float* __restrict__ xnext, const float* __restrict__ base,
    float* __restrict__ out) {
    int gt = blockIdx.x * blockDim.x + threadIdx.x;
    int node = gt >> 6;
    int lane = gt & 63;
    if (node >= NNODES) return;
    int r0 = __builtin_amdgcn_readfirstlane(rowptr[node]);
    int r1 = __builtin_amdgcn_readfirstlane(rowptr[node + 1]);
    float acc0 = 0.f, acc1 = 0.f;
    int j = r0;
    for (; j + 1 < r1; j += 2) {
        int c0 = col[j], c1 = col[j + 1];
        float w0 = dis[c0], w1 = dis[c1];
        acc0 += w0 * xin[(size_t)c0 * DIM + lane];
        acc1 += w1 * xin[(size_t)c1 * DIM + lane];
    }
    if (j < r1) {
        int c = col[j];
        acc0 += dis[c] * xin[(size_t)c * DIM + lane];
    }
    float y = dis[node] * (acc0 + acc1);
    size_t idx = (size_t)node * DIM + lane;
    xnext[idx] = y;
    if (FIRST)
        out[idx] = ALPHA * (base[idx] + y);
    else
        out[idx] += ALPHA * y;
}

// one wave per label edge. W1 staged in LDS. h_j computed by lane j.
__global__ __launch_bounds__(256) void k_mlp(
    const float* __restrict__ out, const int* __restrict__ eli,
    const float* __restrict__ lbl, const float* __restrict__ W1,
    const float* __restrict__ b1, const float* __restrict__ W2,
    const float* __restrict__ b2, float* __restrict__ pred,
    float* __restrict__ partial) {
    __shared__ float w1s[128 * 64];
    __shared__ float wsum[4];
    int tid = threadIdx.x;
    for (int i = tid; i < 128 * 64; i += 256) w1s[i] = W1[i];
    __syncthreads();

    int lane = tid & 63;
    int wid = tid >> 6;
    int gw = blockIdx.x * 4 + wid;
    int nw = gridDim.x * 4;
    float b1v = b1[lane];
    float w2v = W2[lane];
    float b2v = b2[0];
    float lsum = 0.f;

    for (int l = gw; l < NLABEL; l += nw) {
        int s = eli[l];
        int t = eli[NLABEL + l];
        float a = out[(size_t)s * DIM + lane];
        float b = out[(size_t)t * DIM + lane];
        float acc0 = b1v, acc1 = 0.f;
#pragma unroll
        for (int k = 0; k < 64; ++k)
            acc0 += __shfl(a, k) * w1s[k * 64 + lane];
#pragma unroll
        for (int k = 0; k < 64; ++k)
            acc1 += __shfl(b, k) * w1s[(64 + k) * 64 + lane];
        float h = fmaxf(acc0 + acc1, 0.f);
        float p = h * w2v;
#pragma unroll
        for (int off = 32; off >= 1; off >>= 1)
            p += __shfl_xor(p, off);
        float predv = p + b2v;
        if (lane == 0) pred[l] = predv;
        float d = predv - lbl[l];
        lsum += d * d;   // wave-uniform (predv & lbl uniform across lanes)
    }
    if (lane == 0) wsum[wid] = lsum;
    __syncthreads();
    if (tid == 0) partial[blockIdx.x] = wsum[0] + wsum[1] + wsum[2] + wsum[3];
}

__global__ void k_loss(const float* __restrict__ partial, float* __restrict__ lossout,
                       int nblocks) {
    __shared__ float s[512];
    int tid = threadIdx.x;
    s[tid] = (tid < nblocks) ? partial[tid] : 0.f;
    __syncthreads();
    for (int off = 256; off >= 1; off >>= 1) {
        if (tid < off) s[tid] += s[tid + off];
        __syncthreads();
    }
    if (tid == 0) lossout[0] = s[0] / (float)NLABEL;
}

extern "C" void kernel_launch(void* const* d_in, const int* in_sizes, int n_in,
                              void* d_out, int out_size, void* d_ws, size_t ws_size,
                              hipStream_t stream) {
    const int*   ei  = (const int*)d_in[0];    // edge_index [2,E]
    const int*   eli = (const int*)d_in[1];    // edge_label_index [2,L]
    const float* lbl = (const float*)d_in[2];  // edge_label [L]
    const float* emb = (const float*)d_in[3];  // embedding [N,64]
    const float* W1  = (const float*)d_in[4];  // [128,64]
    const float* b1  = (const float*)d_in[5];  // [64]
    const float* W2  = (const float*)d_in[6];  // [64,1]
    const float* b2  = (const float*)d_in[7];  // [1]
    float* outp = (float*)d_out;               // pred[100000] ++ loss[1]

    char* wsb = (char*)d_ws;
    int*   deg    = (int*)wsb + OFF_DEG;
    float* dis    = (float*)wsb + OFF_DIS;
    int*   rowptr = (int*)wsb + OFF_ROWPTR;
    int*   cursor = (int*)wsb + OFF_CURSOR;
    int*   csum   = (int*)wsb + OFF_CSUM;
    int*   coff   = (int*)wsb + OFF_COFF;
    int*   col    = (int*)wsb + OFF_COL;
    float* bufA   = (float*)wsb + OFF_BUFA;
    float* bufB   = (float*)wsb + OFF_BUFB;
    float* outf   = (float*)wsb + OFF_OUT;
    float* part   = (float*)wsb + OFF_PART;

    const int T = 256;
    // degree histogram + norm
    hipLaunchKernelGGL(k_zero_deg, dim3((NNODES + T - 1) / T), dim3(T), 0, stream, deg);
    hipLaunchKernelGGL(k_hist, dim3((NEDGES + T - 1) / T), dim3(T), 0, stream, ei, deg);
    hipLaunchKernelGGL(k_dis, dim3((NNODES + T - 1) / T), dim3(T), 0, stream, deg, dis);
    // CSR build
    hipLaunchKernelGGL(k_scan1, dim3(NCHUNK), dim3(1024), 0, stream, deg, rowptr, csum);
    hipLaunchKernelGGL(k_scan2, dim3(1), dim3(128), 0, stream, csum, coff);
    hipLaunchKernelGGL(k_scan3, dim3((NNODES + T) / T), dim3(T), 0, stream, rowptr, coff, cursor);
    hipLaunchKernelGGL(k_fill, dim3((NEDGES + T - 1) / T), dim3(T), 0, stream, ei, cursor, col);
    // 3 LightGCN layers, out-accumulation fused
    dim3 pgrid((NNODES * 64) / T);
    hipLaunchKernelGGL((k_prop<1>), pgrid, dim3(T), 0, stream, rowptr, col, dis, emb,  bufA, emb, outf);
    hipLaunchKernelGGL((k_prop<0>), pgrid, dim3(T), 0, stream, rowptr, col, dis, bufA, bufB, nullptr, outf);
    hipLaunchKernelGGL((k_prop<0>), pgrid, dim3(T), 0, stream, rowptr, col, dis, bufB, bufA, nullptr, outf);
    // MLP + loss
    const int MLPB = 512;
    hipLaunchKernelGGL(k_mlp, dim3(MLPB), dim3(T), 0, stream, outf, eli, lbl, W1, b1, W2, b2, outp, part);
    hipLaunchKernelGGL(k_loss, dim3(1), dim3(512), 0, stream, part, outp + NLABEL, MLPB);
}

// Round 2
// 594.731 us; speedup vs baseline: 1.0362x; 1.0362x over previous
//
#include <hip/hip_runtime.h>
#include <math.h>

// ---- problem constants (match reference) ----
#define NNODES 100000
#define NEDGES 1600000
#define NLABEL 100000
#define DIM    64
#define ALPHA  0.25f            // 1/(NUM_LAYERS+1)
#define NCHUNK ((NNODES + 1023) / 1024)   // 98

// ---- workspace layout (in 4-byte elements) : total ~91.2 MB ----
constexpr size_t OFF_DEG    = 0;         // int  [100000]
constexpr size_t OFF_DIS    = 100096;    // f32  [100000]
constexpr size_t OFF_ROWPTR = 200192;    // int  [100001]
constexpr size_t OFF_CURSOR = 300288;    // int  [100000]
constexpr size_t OFF_CSUM   = 400384;    // int  [128]
constexpr size_t OFF_COFF   = 400512;    // int  [128]
constexpr size_t OFF_CW     = 400640;    // int2 [1600000] (col, weight) = 3200000 elems
constexpr size_t OFF_BUFA   = 3600640;   // f32  [6400000]
constexpr size_t OFF_BUFB   = 10000640;  // f32  [6400000]
constexpr size_t OFF_OUT    = 16400640;  // f32  [6400000]
constexpr size_t OFF_PART   = 22800640;  // f32  [1024]

__global__ void k_zero_deg(int* __restrict__ deg) {
    int i = blockIdx.x * blockDim.x + threadIdx.x;
    if (i < NNODES) deg[i] = 0;
}

__global__ void k_hist(const int* __restrict__ ei, int* __restrict__ deg) {
    int e = blockIdx.x * blockDim.x + threadIdx.x;
    if (e < NEDGES) atomicAdd(&deg[ei[NEDGES + e]], 1);
}

__global__ void k_dis(const int* __restrict__ deg, float* __restrict__ dis) {
    int i = blockIdx.x * blockDim.x + threadIdx.x;
    if (i < NNODES) {
        int d = deg[i];
        dis[i] = (d > 0) ? rsqrtf((float)d) : 0.0f;
    }
}

// exclusive scan of deg -> rowptr (within 1024-chunks) + per-chunk totals
__global__ void k_scan1(const int* __restrict__ deg, int* __restrict__ rowptr,
                        int* __restrict__ csum) {
    __shared__ int s[1024];
    int tid = threadIdx.x;
    int i = blockIdx.x * 1024 + tid;
    int v = (i < NNODES) ? deg[i] : 0;
    s[tid] = v;
    __syncthreads();
    for (int off = 1; off < 1024; off <<= 1) {
        int t = s[tid];
        if (tid >= off) t += s[tid - off];
        __syncthreads();
        s[tid] = t;
        __syncthreads();
    }
    int incl = s[tid];
    if (i < NNODES) rowptr[i] = incl - v;     // exclusive within chunk
    if (tid == 1023) csum[blockIdx.x] = incl; // chunk total
}

__global__ void k_scan2(const int* __restrict__ csum, int* __restrict__ coff) {
    __shared__ int s[128];
    int tid = threadIdx.x;
    int v = (tid < NCHUNK) ? csum[tid] : 0;
    s[tid] = v;
    __syncthreads();
    for (int off = 1; off < 128; off <<= 1) {
        int t = s[tid];
        if (tid >= off) t += s[tid - off];
        __syncthreads();
        s[tid] = t;
        __syncthreads();
    }
    if (tid < NCHUNK) coff[tid] = s[tid] - v;
}

__global__ void k_scan3(int* __restrict__ rowptr, const int* __restrict__ coff,
                        int* __restrict__ cursor) {
    int i = blockIdx.x * blockDim.x + threadIdx.x;
    if (i < NNODES) {
        int rp = rowptr[i] + coff[i >> 10];
        rowptr[i] = rp;
        cursor[i] = rp;
    }
    if (i == NNODES) rowptr[NNODES] = NEDGES;
}

// fill CSR adjacency as (col, weight=dis[src]) int2 pairs
__global__ void k_fill(const int* __restrict__ ei, const float* __restrict__ dis,
                       int* __restrict__ cursor, int2* __restrict__ cw) {
    int e = blockIdx.x * blockDim.x + threadIdx.x;
    if (e < NEDGES) {
        int s = ei[e];
        int d = ei[NEDGES + e];
        int pos = atomicAdd(&cursor[d], 1);
        int2 v;
        v.x = s;
        v.y = __float_as_int(dis[s]);
        cw[pos] = v;
    }
}

// one wave per node, lane = embedding dim.
// MODE 0: first layer  (xnext = y, out  = ALPHA*(emb+y))
// MODE 1: middle layer (xnext = y, out += ALPHA*y)
// MODE 2: last layer   (out += ALPHA*y only)
template <int MODE>
__global__ __launch_bounds__(256) void k_prop(
    const int* __restrict__ rowptr, const int2* __restrict__ cw,
    const float* __restrict__ dis, const float* __restrict__ xin,
    float* __restrict__ xnext, const float* __restrict__ base,
    float* __restrict__ out) {
    int gt = blockIdx.x * 256 + threadIdx.x;
    int node = gt >> 6;
    int lane = gt & 63;
    if (node >= NNODES) return;
    int r0 = __builtin_amdgcn_readfirstlane(rowptr[node]);
    int r1 = __builtin_amdgcn_readfirstlane(rowptr[node + 1]);
    float a0 = 0.f, a1 = 0.f, a2 = 0.f, a3 = 0.f;
    int j = r0;
    for (; j + 3 < r1; j += 4) {
        int2 e0 = cw[j], e1 = cw[j + 1], e2 = cw[j + 2], e3 = cw[j + 3];
        a0 += __int_as_float(e0.y) * xin[(size_t)e0.x * DIM + lane];
        a1 += __int_as_float(e1.y) * xin[(size_t)e1.x * DIM + lane];
        a2 += __int_as_float(e2.y) * xin[(size_t)e2.x * DIM + lane];
        a3 += __int_as_float(e3.y) * xin[(size_t)e3.x * DIM + lane];
    }
    for (; j < r1; ++j) {
        int2 e = cw[j];
        a0 += __int_as_float(e.y) * xin[(size_t)e.x * DIM + lane];
    }
    float y = dis[node] * ((a0 + a1) + (a2 + a3));
    size_t idx = (size_t)node * DIM + lane;
    if (MODE == 0) {
        xnext[idx] = y;
        out[idx] = ALPHA * (base[idx] + y);
    } else if (MODE == 1) {
        xnext[idx] = y;
        out[idx] += ALPHA * y;
    } else {
        out[idx] += ALPHA * y;
    }
}

// MLP: 2 threads per label (adjacent lanes), each owns 32 of 64 hidden units.
// All accumulator indexing compile-time (no scratch). W1/b1/W2 via L1 (hot 32KB).
__global__ __launch_bounds__(256) void k_mlp(
    const float* __restrict__ outf, const int* __restrict__ eli,
    const float* __restrict__ lbl, const float* __restrict__ W1,
    const float* __restrict__ b1, const float* __restrict__ W2,
    const float* __restrict__ b2, float* __restrict__ pred,
    float* __restrict__ partial) {
    int tid = threadIdx.x;
    int gt = blockIdx.x * 256 + tid;
    int l = gt >> 1;
    int half = gt & 1;
    int j0 = half * 32;
    bool valid = (l < NLABEL);
    int li = valid ? l : 0;
    int s = eli[li];
    int t = eli[NLABEL + li];

    float acc[32];
#pragma unroll
    for (int j = 0; j < 32; ++j) acc[j] = b1[j0 + j];

    const float* xrow = outf + (size_t)s * DIM;
#pragma unroll 1
    for (int side = 0; side < 2; ++side) {
        const float* w1base = W1 + (size_t)side * 64 * 64 + j0;
#pragma unroll 2
        for (int k4 = 0; k4 < 16; ++k4) {
            float4 xv = *(const float4*)(xrow + k4 * 4);
#pragma unroll
            for (int kk = 0; kk < 4; ++kk) {
                float xk = (kk == 0) ? xv.x : (kk == 1) ? xv.y : (kk == 2) ? xv.z : xv.w;
                const float4* wr = (const float4*)(w1base + (size_t)(k4 * 4 + kk) * 64);
#pragma unroll
                for (int m = 0; m < 8; ++m) {
                    float4 wv = wr[m];
                    acc[m * 4 + 0] += xk * wv.x;
                    acc[m * 4 + 1] += xk * wv.y;
                    acc[m * 4 + 2] += xk * wv.z;
                    acc[m * 4 + 3] += xk * wv.w;
                }
            }
        }
        xrow = outf + (size_t)t * DIM;   // second pass: dst row
    }

    float p = 0.f;
#pragma unroll
    for (int j = 0; j < 32; ++j)
        p += fmaxf(acc[j], 0.f) * W2[j0 + j];
    p += __shfl_xor(p, 1);               // combine the two halves of this label

    float lsum = 0.f;
    if (valid && half == 0) {
        float predv = p + b2[0];
        pred[l] = predv;
        float d = predv - lbl[l];
        lsum = d * d;
    }
#pragma unroll
    for (int off = 32; off >= 1; off >>= 1)
        lsum += __shfl_xor(lsum, off);
    __shared__ float ws[4];
    if ((tid & 63) == 0) ws[tid >> 6] = lsum;
    __syncthreads();
    if (tid == 0) partial[blockIdx.x] = (ws[0] + ws[1]) + (ws[2] + ws[3]);
}

__global__ void k_loss(const float* __restrict__ partial, float* __restrict__ lossout,
                       int n) {
    __shared__ float s[512];
    int tid = threadIdx.x;
    float v = 0.f;
    for (int i = tid; i < n; i += 512) v += partial[i];
    s[tid] = v;
    __syncthreads();
    for (int off = 256; off >= 1; off >>= 1) {
        if (tid < off) s[tid] += s[tid + off];
        __syncthreads();
    }
    if (tid == 0) lossout[0] = s[0] / (float)NLABEL;
}

extern "C" void kernel_launch(void* const* d_in, const int* in_sizes, int n_in,
                              void* d_out, int out_size, void* d_ws, size_t ws_size,
                              hipStream_t stream) {
    const int*   ei  = (const int*)d_in[0];    // edge_index [2,E]
    const int*   eli = (const int*)d_in[1];    // edge_label_index [2,L]
    const float* lbl = (const float*)d_in[2];  // edge_label [L]
    const float* emb = (const float*)d_in[3];  // embedding [N,64]
    const float* W1  = (const float*)d_in[4];  // [128,64]
    const float* b1  = (const float*)d_in[5];  // [64]
    const float* W2  = (const float*)d_in[6];  // [64,1]
    const float* b2  = (const float*)d_in[7];  // [1]
    float* outp = (float*)d_out;               // pred[100000] ++ loss[1]

    char* wsb = (char*)d_ws;
    int*   deg    = (int*)wsb + OFF_DEG;
    float* dis    = (float*)wsb + OFF_DIS;
    int*   rowptr = (int*)wsb + OFF_ROWPTR;
    int*   cursor = (int*)wsb + OFF_CURSOR;
    int*   csum   = (int*)wsb + OFF_CSUM;
    int*   coff   = (int*)wsb + OFF_COFF;
    int2*  cw     = (int2*)((int*)wsb + OFF_CW);
    float* bufA   = (float*)wsb + OFF_BUFA;
    float* bufB   = (float*)wsb + OFF_BUFB;
    float* outf   = (float*)wsb + OFF_OUT;
    float* part   = (float*)wsb + OFF_PART;

    const int T = 256;
    hipLaunchKernelGGL(k_zero_deg, dim3((NNODES + T - 1) / T), dim3(T), 0, stream, deg);
    hipLaunchKernelGGL(k_hist, dim3((NEDGES + T - 1) / T), dim3(T), 0, stream, ei, deg);
    hipLaunchKernelGGL(k_dis, dim3((NNODES + T - 1) / T), dim3(T), 0, stream, deg, dis);
    hipLaunchKernelGGL(k_scan1, dim3(NCHUNK), dim3(1024), 0, stream, deg, rowptr, csum);
    hipLaunchKernelGGL(k_scan2, dim3(1), dim3(128), 0, stream, csum, coff);
    hipLaunchKernelGGL(k_scan3, dim3((NNODES + T) / T), dim3(T), 0, stream, rowptr, coff, cursor);
    hipLaunchKernelGGL(k_fill, dim3((NEDGES + T - 1) / T), dim3(T), 0, stream, ei, dis, cursor, cw);

    dim3 pgrid((NNODES * 64) / T);
    hipLaunchKernelGGL((k_prop<0>), pgrid, dim3(T), 0, stream, rowptr, cw, dis, emb,  bufA, emb, outf);
    hipLaunchKernelGGL((k_prop<1>), pgrid, dim3(T), 0, stream, rowptr, cw, dis, bufA, bufB, nullptr, outf);
    hipLaunchKernelGGL((k_prop<2>), pgrid, dim3(T), 0, stream, rowptr, cw, dis, bufB, nullptr, nullptr, outf);

    const int MLPB = (2 * NLABEL + T - 1) / T;   // 782
    hipLaunchKernelGGL(k_mlp, dim3(MLPB), dim3(T), 0, stream, outf, eli, lbl, W1, b1, W2, b2, outp, part);
    hipLaunchKernelGGL(k_loss, dim3(1), dim3(512), 0, stream, part, outp + NLABEL, MLPB);
}

// Round 3
// 390.329 us; speedup vs baseline: 1.5788x; 1.5237x over previous
//
#include <hip/hip_runtime.h>
#include <math.h>

// ---- problem constants (match reference) ----
#define NNODES 100000
#define NEDGES 1600000
#define NLABEL 100000
#define DIM    64
#define ALPHA  0.25f            // 1/(NUM_LAYERS+1)
#define NCHUNK ((NNODES + 1023) / 1024)   // 98

// ---- workspace layout (in 4-byte elements) ----
constexpr size_t OFF_DEG    = 0;         // int  [100000]
constexpr size_t OFF_DIS    = 100096;    // f32  [100000]
constexpr size_t OFF_ROWPTR = 200192;    // int  [100001]
constexpr size_t OFF_CURSOR = 300288;    // int  [100000]
constexpr size_t OFF_CSUM   = 400384;    // int  [128]
constexpr size_t OFF_COFF   = 400512;    // int  [128]
constexpr size_t OFF_CW     = 400640;    // int2 [1600000] = 3200000 elems
constexpr size_t OFF_BUFA   = 3600640;   // f32  [6400000]
constexpr size_t OFF_BUFB   = 10000640;  // f32  [6400000]
constexpr size_t OFF_OUT    = 16400640;  // f32  [6400000]
constexpr size_t OFF_PART   = 22800640;  // f32  [2048]

__global__ void k_zero_deg(int* __restrict__ deg) {
    int i = blockIdx.x * blockDim.x + threadIdx.x;
    if (i < NNODES) deg[i] = 0;
}

__global__ void k_hist(const int* __restrict__ ei, int* __restrict__ deg) {
    int e = blockIdx.x * blockDim.x + threadIdx.x;
    if (e < NEDGES) atomicAdd(&deg[ei[NEDGES + e]], 1);
}

__global__ void k_dis(const int* __restrict__ deg, float* __restrict__ dis) {
    int i = blockIdx.x * blockDim.x + threadIdx.x;
    if (i < NNODES) {
        int d = deg[i];
        dis[i] = (d > 0) ? rsqrtf((float)d) : 0.0f;
    }
}

__global__ void k_scan1(const int* __restrict__ deg, int* __restrict__ rowptr,
                        int* __restrict__ csum) {
    __shared__ int s[1024];
    int tid = threadIdx.x;
    int i = blockIdx.x * 1024 + tid;
    int v = (i < NNODES) ? deg[i] : 0;
    s[tid] = v;
    __syncthreads();
    for (int off = 1; off < 1024; off <<= 1) {
        int t = s[tid];
        if (tid >= off) t += s[tid - off];
        __syncthreads();
        s[tid] = t;
        __syncthreads();
    }
    int incl = s[tid];
    if (i < NNODES) rowptr[i] = incl - v;
    if (tid == 1023) csum[blockIdx.x] = incl;
}

__global__ void k_scan2(const int* __restrict__ csum, int* __restrict__ coff) {
    __shared__ int s[128];
    int tid = threadIdx.x;
    int v = (tid < NCHUNK) ? csum[tid] : 0;
    s[tid] = v;
    __syncthreads();
    for (int off = 1; off < 128; off <<= 1) {
        int t = s[tid];
        if (tid >= off) t += s[tid - off];
        __syncthreads();
        s[tid] = t;
        __syncthreads();
    }
    if (tid < NCHUNK) coff[tid] = s[tid] - v;
}

__global__ void k_scan3(int* __restrict__ rowptr, const int* __restrict__ coff,
                        int* __restrict__ cursor) {
    int i = blockIdx.x * blockDim.x + threadIdx.x;
    if (i < NNODES) {
        int rp = rowptr[i] + coff[i >> 10];
        rowptr[i] = rp;
        cursor[i] = rp;
    }
    if (i == NNODES) rowptr[NNODES] = NEDGES;
}

__global__ void k_fill(const int* __restrict__ ei, const float* __restrict__ dis,
                       int* __restrict__ cursor, int2* __restrict__ cw) {
    int e = blockIdx.x * blockDim.x + threadIdx.x;
    if (e < NEDGES) {
        int s = ei[e];
        int d = ei[NEDGES + e];
        int pos = atomicAdd(&cursor[d], 1);
        int2 v;
        v.x = s;
        v.y = __float_as_int(dis[s]);
        cw[pos] = v;
    }
}

// one wave per node; lanes = 4 edge-groups x 16 lanes; each lane owns a float4
// of the 64-dim row. MODE 0/1: dst = x_next. MODE 2: dst = out fused combine.
template <int MODE>
__global__ __launch_bounds__(256) void k_prop(
    const int* __restrict__ rowptr, const int2* __restrict__ cw,
    const float* __restrict__ dis, const float* __restrict__ xin,
    float* __restrict__ dst, const float* __restrict__ emb,
    const float* __restrict__ x1, const float* __restrict__ x2) {
    int gt = blockIdx.x * 256 + threadIdx.x;
    int node = gt >> 6;
    if (node >= NNODES) return;
    int lane = threadIdx.x & 63;
    int g = lane >> 4;     // edge group 0..3
    int c = lane & 15;     // float4 chunk within row
    int r0 = __builtin_amdgcn_readfirstlane(rowptr[node]);
    int r1 = __builtin_amdgcn_readfirstlane(rowptr[node + 1]);
    float4 acc0 = {0.f, 0.f, 0.f, 0.f}, acc1 = {0.f, 0.f, 0.f, 0.f};
    int j = r0 + g;
    for (; j + 4 < r1; j += 8) {           // 2 edges per group in flight
        int2 e0 = cw[j];
        int2 e1 = cw[j + 4];
        float4 xv0 = *(const float4*)(xin + (size_t)e0.x * DIM + c * 4);
        float4 xv1 = *(const float4*)(xin + (size_t)e1.x * DIM + c * 4);
        float w0 = __int_as_float(e0.y), w1 = __int_as_float(e1.y);
        acc0.x += w0 * xv0.x; acc0.y += w0 * xv0.y;
        acc0.z += w0 * xv0.z; acc0.w += w0 * xv0.w;
        acc1.x += w1 * xv1.x; acc1.y += w1 * xv1.y;
        acc1.z += w1 * xv1.z; acc1.w += w1 * xv1.w;
    }
    for (; j < r1; j += 4) {
        int2 e = cw[j];
        float4 xv = *(const float4*)(xin + (size_t)e.x * DIM + c * 4);
        float w = __int_as_float(e.y);
        acc0.x += w * xv.x; acc0.y += w * xv.y;
        acc0.z += w * xv.z; acc0.w += w * xv.w;
    }
    acc0.x += acc1.x; acc0.y += acc1.y; acc0.z += acc1.z; acc0.w += acc1.w;
    // reduce across the 4 edge groups
    acc0.x += __shfl_xor(acc0.x, 16); acc0.y += __shfl_xor(acc0.y, 16);
    acc0.z += __shfl_xor(acc0.z, 16); acc0.w += __shfl_xor(acc0.w, 16);
    acc0.x += __shfl_xor(acc0.x, 32); acc0.y += __shfl_xor(acc0.y, 32);
    acc0.z += __shfl_xor(acc0.z, 32); acc0.w += __shfl_xor(acc0.w, 32);
    if (lane < 16) {
        float dn = dis[node];
        float4 y;
        y.x = dn * acc0.x; y.y = dn * acc0.y; y.z = dn * acc0.z; y.w = dn * acc0.w;
        size_t idx = (size_t)node * DIM + c * 4;
        if (MODE < 2) {
            *(float4*)(dst + idx) = y;
        } else {
            float4 e = *(const float4*)(emb + idx);
            float4 a = *(const float4*)(x1 + idx);
            float4 b = *(const float4*)(x2 + idx);
            float4 o;
            o.x = ALPHA * (e.x + a.x + b.x + y.x);
            o.y = ALPHA * (e.y + a.y + b.y + y.y);
            o.z = ALPHA * (e.z + a.z + b.z + y.z);
            o.w = ALPHA * (e.w + a.w + b.w + y.w);
            *(float4*)(dst + idx) = o;
        }
    }
}

// LDS-tiled MLP GEMM: 64 labels/block, xs staged k-major, W1 staged, 4x4
// register tile per thread. h = relu([xs|xd] @ W1 + b1); pred = h @ W2 + b2.
__global__ __launch_bounds__(256) void k_mlp(
    const float* __restrict__ outf, const int* __restrict__ eli,
    const float* __restrict__ lbl, const float* __restrict__ W1,
    const float* __restrict__ b1, const float* __restrict__ W2,
    const float* __restrict__ b2, float* __restrict__ pred,
    float* __restrict__ partial) {
    __shared__ float xs[128][68];     // [k][label], pad 4 -> write-conflict-free
    __shared__ float w1s[128 * 64];   // [k][j]
    __shared__ float ws[4];
    int tid = threadIdx.x;
    int lb = blockIdx.x * 64;

    // stage W1 (straight copy)
    {
        const float4* src = (const float4*)W1;
        float4* dst = (float4*)w1s;
        for (int i = tid; i < 2048; i += 256) dst[i] = src[i];
    }
    // gather 64 labels' concat rows, transposed to k-major
    {
        int lab = tid >> 2, q = tid & 3;
        int l = lb + lab;
        int li = (l < NLABEL) ? l : (NLABEL - 1);
        int s = eli[li];
        int t = eli[NLABEL + li];
        const float* srow = outf + (size_t)s * DIM;
        const float* trow = outf + (size_t)t * DIM;
#pragma unroll
        for (int i = 0; i < 8; ++i) {
            int cc = q + 4 * i;      // 0..31 float4 chunk of the 128-float row
            float4 v = (cc < 16) ? *(const float4*)(srow + cc * 4)
                                 : *(const float4*)(trow + (cc - 16) * 4);
            int k = 4 * cc;
            xs[k + 0][lab] = v.x;
            xs[k + 1][lab] = v.y;
            xs[k + 2][lab] = v.z;
            xs[k + 3][lab] = v.w;
        }
    }
    __syncthreads();

    int jcol = tid & 15;   // hidden cols 4*jcol..+3
    int lrow = tid >> 4;   // labels 4*lrow..+3
    float acc[4][4];
#pragma unroll
    for (int a = 0; a < 4; ++a)
#pragma unroll
        for (int b = 0; b < 4; ++b) acc[a][b] = 0.f;

#pragma unroll 4
    for (int k = 0; k < 128; ++k) {
        float4 xv = *(const float4*)(&xs[k][4 * lrow]);
        float4 wv = *(const float4*)(&w1s[k * 64 + 4 * jcol]);
        acc[0][0] += xv.x * wv.x; acc[0][1] += xv.x * wv.y;
        acc[0][2] += xv.x * wv.z; acc[0][3] += xv.x * wv.w;
        acc[1][0] += xv.y * wv.x; acc[1][1] += xv.y * wv.y;
        acc[1][2] += xv.y * wv.z; acc[1][3] += xv.y * wv.w;
        acc[2][0] += xv.z * wv.x; acc[2][1] += xv.z * wv.y;
        acc[2][2] += xv.z * wv.z; acc[2][3] += xv.z * wv.w;
        acc[3][0] += xv.w * wv.x; acc[3][1] += xv.w * wv.y;
        acc[3][2] += xv.w * wv.z; acc[3][3] += xv.w * wv.w;
    }

    float4 b1v = *(const float4*)(b1 + 4 * jcol);
    float4 w2v = *(const float4*)(W2 + 4 * jcol);
    float p[4];
#pragma unroll
    for (int a = 0; a < 4; ++a) {
        p[a] = fmaxf(acc[a][0] + b1v.x, 0.f) * w2v.x
             + fmaxf(acc[a][1] + b1v.y, 0.f) * w2v.y
             + fmaxf(acc[a][2] + b1v.z, 0.f) * w2v.z
             + fmaxf(acc[a][3] + b1v.w, 0.f) * w2v.w;
    }
#pragma unroll
    for (int off = 1; off <= 8; off <<= 1) {
#pragma unroll
        for (int a = 0; a < 4; ++a) p[a] += __shfl_xor(p[a], off);
    }
    float lsum = 0.f;
    if (jcol == 0) {
        float b2v = b2[0];
#pragma unroll
        for (int a = 0; a < 4; ++a) {
            int l = lb + 4 * lrow + a;
            if (l < NLABEL) {
                float predv = p[a] + b2v;
                pred[l] = predv;
                float d = predv - lbl[l];
                lsum += d * d;
            }
        }
    }
    lsum += __shfl_xor(lsum, 16);
    lsum += __shfl_xor(lsum, 32);
    if ((tid & 63) == 0) ws[tid >> 6] = lsum;
    __syncthreads();
    if (tid == 0) partial[blockIdx.x] = (ws[0] + ws[1]) + (ws[2] + ws[3]);
}

__global__ void k_loss(const float* __restrict__ partial, float* __restrict__ lossout,
                       int n) {
    __shared__ float s[512];
    int tid = threadIdx.x;
    float v = 0.f;
    for (int i = tid; i < n; i += 512) v += partial[i];
    s[tid] = v;
    __syncthreads();
    for (int off = 256; off >= 1; off >>= 1) {
        if (tid < off) s[tid] += s[tid + off];
        __syncthreads();
    }
    if (tid == 0) lossout[0] = s[0] / (float)NLABEL;
}

extern "C" void kernel_launch(void* const* d_in, const int* in_sizes, int n_in,
                              void* d_out, int out_size, void* d_ws, size_t ws_size,
                              hipStream_t stream) {
    const int*   ei  = (const int*)d_in[0];
    const int*   eli = (const int*)d_in[1];
    const float* lbl = (const float*)d_in[2];
    const float* emb = (const float*)d_in[3];
    const float* W1  = (const float*)d_in[4];
    const float* b1  = (const float*)d_in[5];
    const float* W2  = (const float*)d_in[6];
    const float* b2  = (const float*)d_in[7];
    float* outp = (float*)d_out;               // pred[100000] ++ loss[1]

    char* wsb = (char*)d_ws;
    int*   deg    = (int*)wsb + OFF_DEG;
    float* dis    = (float*)wsb + OFF_DIS;
    int*   rowptr = (int*)wsb + OFF_ROWPTR;
    int*   cursor = (int*)wsb + OFF_CURSOR;
    int*   csum   = (int*)wsb + OFF_CSUM;
    int*   coff   = (int*)wsb + OFF_COFF;
    int2*  cw     = (int2*)((int*)wsb + OFF_CW);
    float* bufA   = (float*)wsb + OFF_BUFA;
    float* bufB   = (float*)wsb + OFF_BUFB;
    float* outf   = (float*)wsb + OFF_OUT;
    float* part   = (float*)wsb + OFF_PART;

    const int T = 256;
    hipLaunchKernelGGL(k_zero_deg, dim3((NNODES + T - 1) / T), dim3(T), 0, stream, deg);
    hipLaunchKernelGGL(k_hist, dim3((NEDGES + T - 1) / T), dim3(T), 0, stream, ei, deg);
    hipLaunchKernelGGL(k_dis, dim3((NNODES + T - 1) / T), dim3(T), 0, stream, deg, dis);
    hipLaunchKernelGGL(k_scan1, dim3(NCHUNK), dim3(1024), 0, stream, deg, rowptr, csum);
    hipLaunchKernelGGL(k_scan2, dim3(1), dim3(128), 0, stream, csum, coff);
    hipLaunchKernelGGL(k_scan3, dim3((NNODES + T) / T), dim3(T), 0, stream, rowptr, coff, cursor);
    hipLaunchKernelGGL(k_fill, dim3((NEDGES + T - 1) / T), dim3(T), 0, stream, ei, dis, cursor, cw);

    // x1 = P(emb); x2 = P(x1); out = ALPHA*(emb + x1 + x2 + P(x2))
    dim3 pgrid((NNODES * 64) / T);
    hipLaunchKernelGGL((k_prop<0>), pgrid, dim3(T), 0, stream, rowptr, cw, dis, emb,  bufA, nullptr, nullptr, nullptr);
    hipLaunchKernelGGL((k_prop<1>), pgrid, dim3(T), 0, stream, rowptr, cw, dis, bufA, bufB, nullptr, nullptr, nullptr);
    hipLaunchKernelGGL((k_prop<2>), pgrid, dim3(T), 0, stream, rowptr, cw, dis, bufB, outf, emb, bufA, bufB);

    const int MLPB = (NLABEL + 63) / 64;   // 1563
    hipLaunchKernelGGL(k_mlp, dim3(MLPB), dim3(T), 0, stream, outf, eli, lbl, W1, b1, W2, b2, outp, part);
    hipLaunchKernelGGL(k_loss, dim3(1), dim3(512), 0, stream, part, outp + NLABEL, MLPB);
}

// Round 4
// 357.853 us; speedup vs baseline: 1.7221x; 1.0908x over previous
//
#include <hip/hip_runtime.h>
#include <math.h>

// ---- problem constants (match reference) ----
#define NNODES 100000
#define NEDGES 1600000
#define NLABEL 100000
#define DIM    64
#define ALPHA  0.25f            // 1/(NUM_LAYERS+1)
#define NCHUNK ((NNODES + 1023) / 1024)   // 98
#define NB     782               // coarse buckets of 128 nodes (dst >> 7)

// ---- workspace layout (in 4-byte elements) ----
constexpr size_t OFF_DEG    = 0;         // int  [100000]
constexpr size_t OFF_DIS    = 100096;    // f32  [100000]
constexpr size_t OFF_ROWPTR = 200192;    // int  [100001]
constexpr size_t OFF_CURSOR = 300288;    // int  [NB] (bucket cursors)
constexpr size_t OFF_CSUM   = 400384;    // int  [128]
constexpr size_t OFF_COFF   = 400512;    // int  [128]
constexpr size_t OFF_CW     = 400640;    // int2 [1600000] = 3200000 elems
constexpr size_t OFF_BUFA   = 3600640;   // f32  [6400000]  (also aliased as tmp int2[] during fill)
constexpr size_t OFF_BUFB   = 10000640;  // f32  [6400000]
constexpr size_t OFF_OUT    = 16400640;  // f32  [6400000]
constexpr size_t OFF_PART   = 22800640;  // f32  [2048]

__global__ void k_zero_deg(int* __restrict__ deg) {
    int i = blockIdx.x * blockDim.x + threadIdx.x;
    if (i < NNODES) deg[i] = 0;
}

__global__ void k_hist(const int* __restrict__ ei, int* __restrict__ deg) {
    int e = blockIdx.x * blockDim.x + threadIdx.x;
    if (e < NEDGES) atomicAdd(&deg[ei[NEDGES + e]], 1);
}

__global__ void k_dis(const int* __restrict__ deg, float* __restrict__ dis) {
    int i = blockIdx.x * blockDim.x + threadIdx.x;
    if (i < NNODES) {
        int d = deg[i];
        dis[i] = (d > 0) ? rsqrtf((float)d) : 0.0f;
    }
}

__global__ void k_scan1(const int* __restrict__ deg, int* __restrict__ rowptr,
                        int* __restrict__ csum) {
    __shared__ int s[1024];
    int tid = threadIdx.x;
    int i = blockIdx.x * 1024 + tid;
    int v = (i < NNODES) ? deg[i] : 0;
    s[tid] = v;
    __syncthreads();
    for (int off = 1; off < 1024; off <<= 1) {
        int t = s[tid];
        if (tid >= off) t += s[tid - off];
        __syncthreads();
        s[tid] = t;
        __syncthreads();
    }
    int incl = s[tid];
    if (i < NNODES) rowptr[i] = incl - v;
    if (tid == 1023) csum[blockIdx.x] = incl;
}

__global__ void k_scan2(const int* __restrict__ csum, int* __restrict__ coff) {
    __shared__ int s[128];
    int tid = threadIdx.x;
    int v = (tid < NCHUNK) ? csum[tid] : 0;
    s[tid] = v;
    __syncthreads();
    for (int off = 1; off < 128; off <<= 1) {
        int t = s[tid];
        if (tid >= off) t += s[tid - off];
        __syncthreads();
        s[tid] = t;
        __syncthreads();
    }
    if (tid < NCHUNK) coff[tid] = s[tid] - v;
}

// finalize rowptr; init per-bucket write cursors to bucket starts
__global__ void k_scan3(int* __restrict__ rowptr, const int* __restrict__ coff,
                        int* __restrict__ gcursor) {
    int i = blockIdx.x * blockDim.x + threadIdx.x;
    if (i < NNODES) {
        int rp = rowptr[i] + coff[i >> 10];
        rowptr[i] = rp;
        if ((i & 127) == 0) gcursor[i >> 7] = rp;
    }
    if (i == NNODES) rowptr[NNODES] = NEDGES;
}

// fill pass 1: partition edges into 782 coarse buckets (128 nodes each).
// Per-block LDS histogram + one global reserve per (block,bucket) ->
// bucket-contiguous ~128B write runs instead of random 8B scatter.
__global__ __launch_bounds__(256) void k_fill1(
    const int* __restrict__ ei, int* __restrict__ gcursor,
    int2* __restrict__ tmp, int nblk) {
    __shared__ int hist[NB];
    __shared__ int base[NB];
    int tid = threadIdx.x;
    int chunk = (NEDGES + nblk - 1) / nblk;
    int e0 = blockIdx.x * chunk;
    int e1 = min(e0 + chunk, NEDGES);
    for (int i = tid; i < NB; i += 256) hist[i] = 0;
    __syncthreads();
    for (int e = e0 + tid; e < e1; e += 256)
        atomicAdd(&hist[ei[NEDGES + e] >> 7], 1);
    __syncthreads();
    for (int b = tid; b < NB; b += 256) {
        int c = hist[b];
        base[b] = c ? atomicAdd(&gcursor[b], c) : 0;
        hist[b] = 0;
    }
    __syncthreads();
    for (int e = e0 + tid; e < e1; e += 256) {
        int s = ei[e];
        int d = ei[NEDGES + e];
        int bk = d >> 7;
        int loc = atomicAdd(&hist[bk], 1);
        int2 v; v.x = s; v.y = d;
        tmp[base[bk] + loc] = v;
    }
}

// fill pass 2: one block per bucket. Build the bucket's CSR segment in LDS
// (per-node LDS cursors), attach weight dis[src], stream out coalesced.
__global__ __launch_bounds__(256) void k_fill2(
    const int* __restrict__ rowptr, const float* __restrict__ dis,
    const int2* __restrict__ tmp, int2* __restrict__ cw) {
    __shared__ int2 seg[4096];
    __shared__ int cur[128];
    int b = blockIdx.x;
    int tid = threadIdx.x;
    int n0 = b << 7;
    int s0 = rowptr[n0];
    int s1 = rowptr[min(n0 + 128, NNODES)];
    if (tid < 128)
        cur[tid] = rowptr[min(n0 + tid, NNODES)] - s0;
    __syncthreads();
    int n = s1 - s0;
    for (int i = tid; i < n; i += 256) {
        int2 e = tmp[s0 + i];
        int ln = e.y & 127;
        int p = atomicAdd(&cur[ln], 1);
        if (p < 4096) {
            int2 v; v.x = e.x; v.y = __float_as_int(dis[e.x]);
            seg[p] = v;
        }
    }
    __syncthreads();
    for (int i = tid; i < n; i += 256) cw[s0 + i] = seg[i];
}

// one wave per node; lanes = 4 edge-groups x 16 lanes; each lane owns a float4
// of the 64-dim row. MODE 0/1: dst = x_next. MODE 2: dst = out fused combine.
template <int MODE>
__global__ __launch_bounds__(256) void k_prop(
    const int* __restrict__ rowptr, const int2* __restrict__ cw,
    const float* __restrict__ dis, const float* __restrict__ xin,
    float* __restrict__ dst, const float* __restrict__ emb,
    const float* __restrict__ x1, const float* __restrict__ x2) {
    int gt = blockIdx.x * 256 + threadIdx.x;
    int node = gt >> 6;
    if (node >= NNODES) return;
    int lane = threadIdx.x & 63;
    int g = lane >> 4;     // edge group 0..3
    int c = lane & 15;     // float4 chunk within row
    int r0 = __builtin_amdgcn_readfirstlane(rowptr[node]);
    int r1 = __builtin_amdgcn_readfirstlane(rowptr[node + 1]);
    float4 acc0 = {0.f, 0.f, 0.f, 0.f}, acc1 = {0.f, 0.f, 0.f, 0.f};
    int j = r0 + g;
    for (; j + 4 < r1; j += 8) {           // 2 edges per group in flight
        int2 e0 = cw[j];
        int2 e1 = cw[j + 4];
        float4 xv0 = *(const float4*)(xin + (size_t)e0.x * DIM + c * 4);
        float4 xv1 = *(const float4*)(xin + (size_t)e1.x * DIM + c * 4);
        float w0 = __int_as_float(e0.y), w1 = __int_as_float(e1.y);
        acc0.x += w0 * xv0.x; acc0.y += w0 * xv0.y;
        acc0.z += w0 * xv0.z; acc0.w += w0 * xv0.w;
        acc1.x += w1 * xv1.x; acc1.y += w1 * xv1.y;
        acc1.z += w1 * xv1.z; acc1.w += w1 * xv1.w;
    }
    for (; j < r1; j += 4) {
        int2 e = cw[j];
        float4 xv = *(const float4*)(xin + (size_t)e.x * DIM + c * 4);
        float w = __int_as_float(e.y);
        acc0.x += w * xv.x; acc0.y += w * xv.y;
        acc0.z += w * xv.z; acc0.w += w * xv.w;
    }
    acc0.x += acc1.x; acc0.y += acc1.y; acc0.z += acc1.z; acc0.w += acc1.w;
    acc0.x += __shfl_xor(acc0.x, 16); acc0.y += __shfl_xor(acc0.y, 16);
    acc0.z += __shfl_xor(acc0.z, 16); acc0.w += __shfl_xor(acc0.w, 16);
    acc0.x += __shfl_xor(acc0.x, 32); acc0.y += __shfl_xor(acc0.y, 32);
    acc0.z += __shfl_xor(acc0.z, 32); acc0.w += __shfl_xor(acc0.w, 32);
    if (lane < 16) {
        float dn = dis[node];
        float4 y;
        y.x = dn * acc0.x; y.y = dn * acc0.y; y.z = dn * acc0.z; y.w = dn * acc0.w;
        size_t idx = (size_t)node * DIM + c * 4;
        if (MODE < 2) {
            *(float4*)(dst + idx) = y;
        } else {
            float4 e = *(const float4*)(emb + idx);
            float4 a = *(const float4*)(x1 + idx);
            float4 b = *(const float4*)(x2 + idx);
            float4 o;
            o.x = ALPHA * (e.x + a.x + b.x + y.x);
            o.y = ALPHA * (e.y + a.y + b.y + y.y);
            o.z = ALPHA * (e.z + a.z + b.z + y.z);
            o.w = ALPHA * (e.w + a.w + b.w + y.w);
            *(float4*)(dst + idx) = o;
        }
    }
}

// LDS-tiled MLP GEMM: 64 labels/block, xs staged k-major, W1 staged, 4x4
// register tile per thread. h = relu([xs|xd] @ W1 + b1); pred = h @ W2 + b2.
__global__ __launch_bounds__(256) void k_mlp(
    const float* __restrict__ outf, const int* __restrict__ eli,
    const float* __restrict__ lbl, const float* __restrict__ W1,
    const float* __restrict__ b1, const float* __restrict__ W2,
    const float* __restrict__ b2, float* __restrict__ pred,
    float* __restrict__ partial) {
    __shared__ float xs[128][68];
    __shared__ float w1s[128 * 64];
    __shared__ float ws[4];
    int tid = threadIdx.x;
    int lb = blockIdx.x * 64;

    {
        const float4* src = (const float4*)W1;
        float4* dst = (float4*)w1s;
        for (int i = tid; i < 2048; i += 256) dst[i] = src[i];
    }
    {
        int lab = tid >> 2, q = tid & 3;
        int l = lb + lab;
        int li = (l < NLABEL) ? l : (NLABEL - 1);
        int s = eli[li];
        int t = eli[NLABEL + li];
        const float* srow = outf + (size_t)s * DIM;
        const float* trow = outf + (size_t)t * DIM;
#pragma unroll
        for (int i = 0; i < 8; ++i) {
            int cc = q + 4 * i;
            float4 v = (cc < 16) ? *(const float4*)(srow + cc * 4)
                                 : *(const float4*)(trow + (cc - 16) * 4);
            int k = 4 * cc;
            xs[k + 0][lab] = v.x;
            xs[k + 1][lab] = v.y;
            xs[k + 2][lab] = v.z;
            xs[k + 3][lab] = v.w;
        }
    }
    __syncthreads();

    int jcol = tid & 15;
    int lrow = tid >> 4;
    float acc[4][4];
#pragma unroll
    for (int a = 0; a < 4; ++a)
#pragma unroll
        for (int b = 0; b < 4; ++b) acc[a][b] = 0.f;

#pragma unroll 4
    for (int k = 0; k < 128; ++k) {
        float4 xv = *(const float4*)(&xs[k][4 * lrow]);
        float4 wv = *(const float4*)(&w1s[k * 64 + 4 * jcol]);
        acc[0][0] += xv.x * wv.x; acc[0][1] += xv.x * wv.y;
        acc[0][2] += xv.x * wv.z; acc[0][3] += xv.x * wv.w;
        acc[1][0] += xv.y * wv.x; acc[1][1] += xv.y * wv.y;
        acc[1][2] += xv.y * wv.z; acc[1][3] += xv.y * wv.w;
        acc[2][0] += xv.z * wv.x; acc[2][1] += xv.z * wv.y;
        acc[2][2] += xv.z * wv.z; acc[2][3] += xv.z * wv.w;
        acc[3][0] += xv.w * wv.x; acc[3][1] += xv.w * wv.y;
        acc[3][2] += xv.w * wv.z; acc[3][3] += xv.w * wv.w;
    }

    float4 b1v = *(const float4*)(b1 + 4 * jcol);
    float4 w2v = *(const float4*)(W2 + 4 * jcol);
    float p[4];
#pragma unroll
    for (int a = 0; a < 4; ++a) {
        p[a] = fmaxf(acc[a][0] + b1v.x, 0.f) * w2v.x
             + fmaxf(acc[a][1] + b1v.y, 0.f) * w2v.y
             + fmaxf(acc[a][2] + b1v.z, 0.f) * w2v.z
             + fmaxf(acc[a][3] + b1v.w, 0.f) * w2v.w;
    }
#pragma unroll
    for (int off = 1; off <= 8; off <<= 1) {
#pragma unroll
        for (int a = 0; a < 4; ++a) p[a] += __shfl_xor(p[a], off);
    }
    float lsum = 0.f;
    if (jcol == 0) {
        float b2v = b2[0];
#pragma unroll
        for (int a = 0; a < 4; ++a) {
            int l = lb + 4 * lrow + a;
            if (l < NLABEL) {
                float predv = p[a] + b2v;
                pred[l] = predv;
                float d = predv - lbl[l];
                lsum += d * d;
            }
        }
    }
    lsum += __shfl_xor(lsum, 16);
    lsum += __shfl_xor(lsum, 32);
    if ((tid & 63) == 0) ws[tid >> 6] = lsum;
    __syncthreads();
    if (tid == 0) partial[blockIdx.x] = (ws[0] + ws[1]) + (ws[2] + ws[3]);
}

__global__ void k_loss(const float* __restrict__ partial, float* __restrict__ lossout,
                       int n) {
    __shared__ float s[512];
    int tid = threadIdx.x;
    float v = 0.f;
    for (int i = tid; i < n; i += 512) v += partial[i];
    s[tid] = v;
    __syncthreads();
    for (int off = 256; off >= 1; off >>= 1) {
        if (tid < off) s[tid] += s[tid + off];
        __syncthreads();
    }
    if (tid == 0) lossout[0] = s[0] / (float)NLABEL;
}

extern "C" void kernel_launch(void* const* d_in, const int* in_sizes, int n_in,
                              void* d_out, int out_size, void* d_ws, size_t ws_size,
                              hipStream_t stream) {
    const int*   ei  = (const int*)d_in[0];
    const int*   eli = (const int*)d_in[1];
    const float* lbl = (const float*)d_in[2];
    const float* emb = (const float*)d_in[3];
    const float* W1  = (const float*)d_in[4];
    const float* b1  = (const float*)d_in[5];
    const float* W2  = (const float*)d_in[6];
    const float* b2  = (const float*)d_in[7];
    float* outp = (float*)d_out;               // pred[100000] ++ loss[1]

    char* wsb = (char*)d_ws;
    int*   deg    = (int*)wsb + OFF_DEG;
    float* dis    = (float*)wsb + OFF_DIS;
    int*   rowptr = (int*)wsb + OFF_ROWPTR;
    int*   gcur   = (int*)wsb + OFF_CURSOR;
    int*   csum   = (int*)wsb + OFF_CSUM;
    int*   coff   = (int*)wsb + OFF_COFF;
    int2*  cw     = (int2*)((int*)wsb + OFF_CW);
    float* bufA   = (float*)wsb + OFF_BUFA;
    float* bufB   = (float*)wsb + OFF_BUFB;
    float* outf   = (float*)wsb + OFF_OUT;
    float* part   = (float*)wsb + OFF_PART;
    int2*  tmp    = (int2*)bufA;               // alias: free until k_prop<0>

    const int T = 256;
    hipLaunchKernelGGL(k_zero_deg, dim3((NNODES + T - 1) / T), dim3(T), 0, stream, deg);
    hipLaunchKernelGGL(k_hist, dim3((NEDGES + T - 1) / T), dim3(T), 0, stream, ei, deg);
    hipLaunchKernelGGL(k_dis, dim3((NNODES + T - 1) / T), dim3(T), 0, stream, deg, dis);
    hipLaunchKernelGGL(k_scan1, dim3(NCHUNK), dim3(1024), 0, stream, deg, rowptr, csum);
    hipLaunchKernelGGL(k_scan2, dim3(1), dim3(128), 0, stream, csum, coff);
    hipLaunchKernelGGL(k_scan3, dim3((NNODES + T) / T), dim3(T), 0, stream, rowptr, coff, gcur);
    const int NBLK1 = 128;
    hipLaunchKernelGGL(k_fill1, dim3(NBLK1), dim3(T), 0, stream, ei, gcur, tmp, NBLK1);
    hipLaunchKernelGGL(k_fill2, dim3(NB), dim3(T), 0, stream, rowptr, dis, tmp, cw);

    // x1 = P(emb); x2 = P(x1); out = ALPHA*(emb + x1 + x2 + P(x2))
    dim3 pgrid((NNODES * 64) / T);
    hipLaunchKernelGGL((k_prop<0>), pgrid, dim3(T), 0, stream, rowptr, cw, dis, emb,  bufA, nullptr, nullptr, nullptr);
    hipLaunchKernelGGL((k_prop<1>), pgrid, dim3(T), 0, stream, rowptr, cw, dis, bufA, bufB, nullptr, nullptr, nullptr);
    hipLaunchKernelGGL((k_prop<2>), pgrid, dim3(T), 0, stream, rowptr, cw, dis, bufB, outf, emb, bufA, bufB);

    const int MLPB = (NLABEL + 63) / 64;   // 1563
    hipLaunchKernelGGL(k_mlp, dim3(MLPB), dim3(T), 0, stream, outf, eli, lbl, W1, b1, W2, b2, outp, part);
    hipLaunchKernelGGL(k_loss, dim3(1), dim3(512), 0, stream, part, outp + NLABEL, MLPB);
}

// Round 5
// 322.508 us; speedup vs baseline: 1.9108x; 1.1096x over previous
//
#include <hip/hip_runtime.h>
#include <hip/hip_fp16.h>
#include <math.h>

// ---- problem constants (match reference) ----
#define NNODES 100000
#define NEDGES 1600000
#define NLABEL 100000
#define DIM    64
#define ALPHA  0.25f            // 1/(NUM_LAYERS+1)
#define NCHUNK ((NNODES + 1023) / 1024)   // 98
#define NB     782               // coarse buckets of 128 nodes (dst >> 7)

// ---- workspace layout (u32 words) ----
constexpr size_t OFF_DEG    = 0;         // int  [100000]
constexpr size_t OFF_DIS    = 100096;    // f32  [100000]
constexpr size_t OFF_ROWPTR = 200192;    // int  [100001]
constexpr size_t OFF_CURSOR = 300288;    // int  [NB]
constexpr size_t OFF_CSUM   = 400384;    // int  [128]
constexpr size_t OFF_COFF   = 400512;    // int  [128]
constexpr size_t OFF_CW     = 400640;    // int2 [1600000] = 3200000 words
constexpr size_t OFF_EMB16  = 3600640;   // half [6400000] = 3200000 words
constexpr size_t OFF_X1     = 6800640;   // half [6400000] (aliased by tmp during fill)
constexpr size_t OFF_X2     = 10000640;  // half [6400000]
constexpr size_t OFF_OUTF16 = 13200640;  // half [6400000]
constexpr size_t OFF_PART   = 16400640;  // f32  [2048]

__global__ void k_zero_deg(int* __restrict__ deg) {
    int i = blockIdx.x * blockDim.x + threadIdx.x;
    if (i < NNODES) deg[i] = 0;
}

__global__ void k_hist(const int* __restrict__ ei, int* __restrict__ deg) {
    int e = blockIdx.x * blockDim.x + threadIdx.x;
    if (e < NEDGES) atomicAdd(&deg[ei[NEDGES + e]], 1);
}

__global__ void k_dis(const int* __restrict__ deg, float* __restrict__ dis) {
    int i = blockIdx.x * blockDim.x + threadIdx.x;
    if (i < NNODES) {
        int d = deg[i];
        dis[i] = (d > 0) ? rsqrtf((float)d) : 0.0f;
    }
}

// convert fp32 embedding -> fp16
__global__ void k_cvt(const float* __restrict__ emb, __half* __restrict__ emb16) {
    int i = blockIdx.x * blockDim.x + threadIdx.x;   // one float4 / thread
    if (i < (NNODES * DIM) / 4) {
        float4 v = ((const float4*)emb)[i];
        __half2 h0 = __float22half2_rn(make_float2(v.x, v.y));
        __half2 h1 = __float22half2_rn(make_float2(v.z, v.w));
        float2 bits;
        ((__half2*)&bits)[0] = h0;
        ((__half2*)&bits)[1] = h1;
        ((float2*)emb16)[i] = bits;
    }
}

__global__ void k_scan1(const int* __restrict__ deg, int* __restrict__ rowptr,
                        int* __restrict__ csum) {
    __shared__ int s[1024];
    int tid = threadIdx.x;
    int i = blockIdx.x * 1024 + tid;
    int v = (i < NNODES) ? deg[i] : 0;
    s[tid] = v;
    __syncthreads();
    for (int off = 1; off < 1024; off <<= 1) {
        int t = s[tid];
        if (tid >= off) t += s[tid - off];
        __syncthreads();
        s[tid] = t;
        __syncthreads();
    }
    int incl = s[tid];
    if (i < NNODES) rowptr[i] = incl - v;
    if (tid == 1023) csum[blockIdx.x] = incl;
}

__global__ void k_scan2(const int* __restrict__ csum, int* __restrict__ coff) {
    __shared__ int s[128];
    int tid = threadIdx.x;
    int v = (tid < NCHUNK) ? csum[tid] : 0;
    s[tid] = v;
    __syncthreads();
    for (int off = 1; off < 128; off <<= 1) {
        int t = s[tid];
        if (tid >= off) t += s[tid - off];
        __syncthreads();
        s[tid] = t;
        __syncthreads();
    }
    if (tid < NCHUNK) coff[tid] = s[tid] - v;
}

__global__ void k_scan3(int* __restrict__ rowptr, const int* __restrict__ coff,
                        int* __restrict__ gcursor) {
    int i = blockIdx.x * blockDim.x + threadIdx.x;
    if (i < NNODES) {
        int rp = rowptr[i] + coff[i >> 10];
        rowptr[i] = rp;
        if ((i & 127) == 0) gcursor[i >> 7] = rp;
    }
    if (i == NNODES) rowptr[NNODES] = NEDGES;
}

// fill pass 1: partition edges into NB coarse buckets (128 dst-nodes each)
__global__ __launch_bounds__(256) void k_fill1(
    const int* __restrict__ ei, int* __restrict__ gcursor,
    int2* __restrict__ tmp, int nblk) {
    __shared__ int hist[NB];
    __shared__ int base[NB];
    int tid = threadIdx.x;
    int chunk = (NEDGES + nblk - 1) / nblk;
    int e0 = blockIdx.x * chunk;
    int e1 = min(e0 + chunk, NEDGES);
    for (int i = tid; i < NB; i += 256) hist[i] = 0;
    __syncthreads();
    for (int e = e0 + tid; e < e1; e += 256)
        atomicAdd(&hist[ei[NEDGES + e] >> 7], 1);
    __syncthreads();
    for (int b = tid; b < NB; b += 256) {
        int c = hist[b];
        base[b] = c ? atomicAdd(&gcursor[b], c) : 0;
        hist[b] = 0;
    }
    __syncthreads();
    for (int e = e0 + tid; e < e1; e += 256) {
        int s = ei[e];
        int d = ei[NEDGES + e];
        int bk = d >> 7;
        int loc = atomicAdd(&hist[bk], 1);
        int2 v; v.x = s; v.y = d;
        tmp[base[bk] + loc] = v;
    }
}

// fill pass 2: per bucket, build CSR segment in LDS, attach weight, stream out
__global__ __launch_bounds__(256) void k_fill2(
    const int* __restrict__ rowptr, const float* __restrict__ dis,
    const int2* __restrict__ tmp, int2* __restrict__ cw) {
    __shared__ int2 seg[4096];
    __shared__ int cur[128];
    int b = blockIdx.x;
    int tid = threadIdx.x;
    int n0 = b << 7;
    int s0 = rowptr[n0];
    int s1 = rowptr[min(n0 + 128, NNODES)];
    if (tid < 128)
        cur[tid] = rowptr[min(n0 + tid, NNODES)] - s0;
    __syncthreads();
    int n = s1 - s0;
    for (int i = tid; i < n; i += 256) {
        int2 e = tmp[s0 + i];
        int ln = e.y & 127;
        int p = atomicAdd(&cur[ln], 1);
        if (p < 4096) {
            int2 v; v.x = e.x; v.y = __float_as_int(dis[e.x]);
            seg[p] = v;
        }
    }
    __syncthreads();
    for (int i = tid; i < n; i += 256) cw[s0 + i] = seg[i];
}

// one wave per node; 4 edge-groups x 16 lanes; each lane owns 4 dims (8 B fp16).
// MODE 0/1: dst = x_next (fp16). MODE 2: dst = out = ALPHA*(emb+x1+x2+y) (fp16).
template <int MODE>
__global__ __launch_bounds__(256) void k_prop(
    const int* __restrict__ rowptr, const int2* __restrict__ cw,
    const float* __restrict__ dis, const __half* __restrict__ xin,
    __half* __restrict__ dst, const __half* __restrict__ emb16,
    const __half* __restrict__ x1, const __half* __restrict__ x2) {
    int gt = blockIdx.x * 256 + threadIdx.x;
    int node = gt >> 6;
    if (node >= NNODES) return;
    int lane = threadIdx.x & 63;
    int g = lane >> 4;     // edge group 0..3
    int c = lane & 15;     // 4-dim chunk within row
    int r0 = __builtin_amdgcn_readfirstlane(rowptr[node]);
    int r1 = __builtin_amdgcn_readfirstlane(rowptr[node + 1]);
    float4 acc0 = {0.f, 0.f, 0.f, 0.f}, acc1 = {0.f, 0.f, 0.f, 0.f};
    int j = r0 + g;
    for (; j + 4 < r1; j += 8) {           // 2 edges per group in flight
        int2 e0 = cw[j];
        int2 e1 = cw[j + 4];
        float2 r0v = *(const float2*)(xin + (size_t)e0.x * DIM + c * 4);
        float2 r1v = *(const float2*)(xin + (size_t)e1.x * DIM + c * 4);
        float w0 = __int_as_float(e0.y), w1 = __int_as_float(e1.y);
        float2 f0 = __half22float2(((__half2*)&r0v)[0]);
        float2 f1 = __half22float2(((__half2*)&r0v)[1]);
        float2 f2 = __half22float2(((__half2*)&r1v)[0]);
        float2 f3 = __half22float2(((__half2*)&r1v)[1]);
        acc0.x += w0 * f0.x; acc0.y += w0 * f0.y;
        acc0.z += w0 * f1.x; acc0.w += w0 * f1.y;
        acc1.x += w1 * f2.x; acc1.y += w1 * f2.y;
        acc1.z += w1 * f3.x; acc1.w += w1 * f3.y;
    }
    for (; j < r1; j += 4) {
        int2 e = cw[j];
        float2 rv = *(const float2*)(xin + (size_t)e.x * DIM + c * 4);
        float w = __int_as_float(e.y);
        float2 f0 = __half22float2(((__half2*)&rv)[0]);
        float2 f1 = __half22float2(((__half2*)&rv)[1]);
        acc0.x += w * f0.x; acc0.y += w * f0.y;
        acc0.z += w * f1.x; acc0.w += w * f1.y;
    }
    acc0.x += acc1.x; acc0.y += acc1.y; acc0.z += acc1.z; acc0.w += acc1.w;
    acc0.x += __shfl_xor(acc0.x, 16); acc0.y += __shfl_xor(acc0.y, 16);
    acc0.z += __shfl_xor(acc0.z, 16); acc0.w += __shfl_xor(acc0.w, 16);
    acc0.x += __shfl_xor(acc0.x, 32); acc0.y += __shfl_xor(acc0.y, 32);
    acc0.z += __shfl_xor(acc0.z, 32); acc0.w += __shfl_xor(acc0.w, 32);
    if (lane < 16) {
        float dn = dis[node];
        float yx = dn * acc0.x, yy = dn * acc0.y;
        float yz = dn * acc0.z, yw = dn * acc0.w;
        size_t idx = (size_t)node * DIM + c * 4;
        if (MODE == 2) {
            float2 eb = *(const float2*)(emb16 + idx);
            float2 ab = *(const float2*)(x1 + idx);
            float2 bb = *(const float2*)(x2 + idx);
            float2 e0 = __half22float2(((__half2*)&eb)[0]);
            float2 e1 = __half22float2(((__half2*)&eb)[1]);
            float2 a0 = __half22float2(((__half2*)&ab)[0]);
            float2 a1 = __half22float2(((__half2*)&ab)[1]);
            float2 b0 = __half22float2(((__half2*)&bb)[0]);
            float2 b1 = __half22float2(((__half2*)&bb)[1]);
            yx = ALPHA * (e0.x + a0.x + b0.x + yx);
            yy = ALPHA * (e0.y + a0.y + b0.y + yy);
            yz = ALPHA * (e1.x + a1.x + b1.x + yz);
            yw = ALPHA * (e1.y + a1.y + b1.y + yw);
        }
        float2 bits;
        ((__half2*)&bits)[0] = __float22half2_rn(make_float2(yx, yy));
        ((__half2*)&bits)[1] = __float22half2_rn(make_float2(yz, yw));
        *(float2*)(dst + idx) = bits;
    }
}

// LDS-tiled MLP GEMM over fp16 outf: 64 labels/block, xs k-major fp32 in LDS.
__global__ __launch_bounds__(256) void k_mlp(
    const __half* __restrict__ outf, const int* __restrict__ eli,
    const float* __restrict__ lbl, const float* __restrict__ W1,
    const float* __restrict__ b1, const float* __restrict__ W2,
    const float* __restrict__ b2, float* __restrict__ pred,
    float* __restrict__ partial) {
    __shared__ float xs[128][68];
    __shared__ float w1s[128 * 64];
    __shared__ float ws[4];
    int tid = threadIdx.x;
    int lb = blockIdx.x * 64;

    {
        const float4* src = (const float4*)W1;
        float4* dst = (float4*)w1s;
        for (int i = tid; i < 2048; i += 256) dst[i] = src[i];
    }
    {
        int lab = tid >> 2, q = tid & 3;
        int l = lb + lab;
        int li = (l < NLABEL) ? l : (NLABEL - 1);
        int s = eli[li];
        int t = eli[NLABEL + li];
        const __half* srow = outf + (size_t)s * DIM;
        const __half* trow = outf + (size_t)t * DIM;
#pragma unroll
        for (int i = 0; i < 4; ++i) {
            int cc = q + 4 * i;           // 16B chunk 0..15 of the 256B concat row
            const __half* row = (cc < 8) ? srow + cc * 8 : trow + (cc - 8) * 8;
            float4 raw = *(const float4*)row;   // 8 halfs
            __half2* hp = (__half2*)&raw;
            int k = 8 * cc;
            float2 f;
            f = __half22float2(hp[0]); xs[k + 0][lab] = f.x; xs[k + 1][lab] = f.y;
            f = __half22float2(hp[1]); xs[k + 2][lab] = f.x; xs[k + 3][lab] = f.y;
            f = __half22float2(hp[2]); xs[k + 4][lab] = f.x; xs[k + 5][lab] = f.y;
            f = __half22float2(hp[3]); xs[k + 6][lab] = f.x; xs[k + 7][lab] = f.y;
        }
    }
    __syncthreads();

    int jcol = tid & 15;
    int lrow = tid >> 4;
    float acc[4][4];
#pragma unroll
    for (int a = 0; a < 4; ++a)
#pragma unroll
        for (int b = 0; b < 4; ++b) acc[a][b] = 0.f;

#pragma unroll 4
    for (int k = 0; k < 128; ++k) {
        float4 xv = *(const float4*)(&xs[k][4 * lrow]);
        float4 wv = *(const float4*)(&w1s[k * 64 + 4 * jcol]);
        acc[0][0] += xv.x * wv.x; acc[0][1] += xv.x * wv.y;
        acc[0][2] += xv.x * wv.z; acc[0][3] += xv.x * wv.w;
        acc[1][0] += xv.y * wv.x; acc[1][1] += xv.y * wv.y;
        acc[1][2] += xv.y * wv.z; acc[1][3] += xv.y * wv.w;
        acc[2][0] += xv.z * wv.x; acc[2][1] += xv.z * wv.y;
        acc[2][2] += xv.z * wv.z; acc[2][3] += xv.z * wv.w;
        acc[3][0] += xv.w * wv.x; acc[3][1] += xv.w * wv.y;
        acc[3][2] += xv.w * wv.z; acc[3][3] += xv.w * wv.w;
    }

    float4 b1v = *(const float4*)(b1 + 4 * jcol);
    float4 w2v = *(const float4*)(W2 + 4 * jcol);
    float p[4];
#pragma unroll
    for (int a = 0; a < 4; ++a) {
        p[a] = fmaxf(acc[a][0] + b1v.x, 0.f) * w2v.x
             + fmaxf(acc[a][1] + b1v.y, 0.f) * w2v.y
             + fmaxf(acc[a][2] + b1v.z, 0.f) * w2v.z
             + fmaxf(acc[a][3] + b1v.w, 0.f) * w2v.w;
    }
#pragma unroll
    for (int off = 1; off <= 8; off <<= 1) {
#pragma unroll
        for (int a = 0; a < 4; ++a) p[a] += __shfl_xor(p[a], off);
    }
    float lsum = 0.f;
    if (jcol == 0) {
        float b2v = b2[0];
#pragma unroll
        for (int a = 0; a < 4; ++a) {
            int l = lb + 4 * lrow + a;
            if (l < NLABEL) {
                float predv = p[a] + b2v;
                pred[l] = predv;
                float d = predv - lbl[l];
                lsum += d * d;
            }
        }
    }
    lsum += __shfl_xor(lsum, 16);
    lsum += __shfl_xor(lsum, 32);
    if ((tid & 63) == 0) ws[tid >> 6] = lsum;
    __syncthreads();
    if (tid == 0) partial[blockIdx.x] = (ws[0] + ws[1]) + (ws[2] + ws[3]);
}

__global__ void k_loss(const float* __restrict__ partial, float* __restrict__ lossout,
                       int n) {
    __shared__ float s[512];
    int tid = threadIdx.x;
    float v = 0.f;
    for (int i = tid; i < n; i += 512) v += partial[i];
    s[tid] = v;
    __syncthreads();
    for (int off = 256; off >= 1; off >>= 1) {
        if (tid < off) s[tid] += s[tid + off];
        __syncthreads();
    }
    if (tid == 0) lossout[0] = s[0] / (float)NLABEL;
}

extern "C" void kernel_launch(void* const* d_in, const int* in_sizes, int n_in,
                              void* d_out, int out_size, void* d_ws, size_t ws_size,
                              hipStream_t stream) {
    const int*   ei  = (const int*)d_in[0];
    const int*   eli = (const int*)d_in[1];
    const float* lbl = (const float*)d_in[2];
    const float* emb = (const float*)d_in[3];
    const float* W1  = (const float*)d_in[4];
    const float* b1  = (const float*)d_in[5];
    const float* W2  = (const float*)d_in[6];
    const float* b2  = (const float*)d_in[7];
    float* outp = (float*)d_out;               // pred[100000] ++ loss[1]

    char* wsb = (char*)d_ws;
    int*    deg    = (int*)wsb + OFF_DEG;
    float*  dis    = (float*)wsb + OFF_DIS;
    int*    rowptr = (int*)wsb + OFF_ROWPTR;
    int*    gcur   = (int*)wsb + OFF_CURSOR;
    int*    csum   = (int*)wsb + OFF_CSUM;
    int*    coff   = (int*)wsb + OFF_COFF;
    int2*   cw     = (int2*)((int*)wsb + OFF_CW);
    __half* emb16  = (__half*)((int*)wsb + OFF_EMB16);
    __half* x1     = (__half*)((int*)wsb + OFF_X1);
    __half* x2     = (__half*)((int*)wsb + OFF_X2);
    __half* outf   = (__half*)((int*)wsb + OFF_OUTF16);
    float*  part   = (float*)wsb + OFF_PART;
    int2*   tmp    = (int2*)x1;                // alias: free until k_prop<0>

    const int T = 256;
    hipLaunchKernelGGL(k_zero_deg, dim3((NNODES + T - 1) / T), dim3(T), 0, stream, deg);
    hipLaunchKernelGGL(k_hist, dim3((NEDGES + T - 1) / T), dim3(T), 0, stream, ei, deg);
    hipLaunchKernelGGL(k_dis, dim3((NNODES + T - 1) / T), dim3(T), 0, stream, deg, dis);
    hipLaunchKernelGGL(k_cvt, dim3((NNODES * DIM / 4 + T - 1) / T), dim3(T), 0, stream, emb, emb16);
    hipLaunchKernelGGL(k_scan1, dim3(NCHUNK), dim3(1024), 0, stream, deg, rowptr, csum);
    hipLaunchKernelGGL(k_scan2, dim3(1), dim3(128), 0, stream, csum, coff);
    hipLaunchKernelGGL(k_scan3, dim3((NNODES + T) / T), dim3(T), 0, stream, rowptr, coff, gcur);
    const int NBLK1 = 128;
    hipLaunchKernelGGL(k_fill1, dim3(NBLK1), dim3(T), 0, stream, ei, gcur, tmp, NBLK1);
    hipLaunchKernelGGL(k_fill2, dim3(NB), dim3(T), 0, stream, rowptr, dis, tmp, cw);

    // x1 = P(emb); x2 = P(x1); outf = ALPHA*(emb + x1 + x2 + P(x2))   [all fp16]
    dim3 pgrid((NNODES * 64) / T);
    hipLaunchKernelGGL((k_prop<0>), pgrid, dim3(T), 0, stream, rowptr, cw, dis, emb16, x1,   nullptr, nullptr, nullptr);
    hipLaunchKernelGGL((k_prop<1>), pgrid, dim3(T), 0, stream, rowptr, cw, dis, x1,    x2,   nullptr, nullptr, nullptr);
    hipLaunchKernelGGL((k_prop<2>), pgrid, dim3(T), 0, stream, rowptr, cw, dis, x2,    outf, emb16, x1, x2);

    const int MLPB = (NLABEL + 63) / 64;   // 1563
    hipLaunchKernelGGL(k_mlp, dim3(MLPB), dim3(T), 0, stream, outf, eli, lbl, W1, b1, W2, b2, outp, part);
    hipLaunchKernelGGL(k_loss, dim3(1), dim3(512), 0, stream, part, outp + NLABEL, MLPB);
}

// Round 6
// 267.041 us; speedup vs baseline: 2.3077x; 1.2077x over previous
//
#include <hip/hip_runtime.h>
#include <hip/hip_fp16.h>
#include <math.h>

// ---- problem constants (match reference) ----
#define NNODES 100000
#define NEDGES 1600000
#define NLABEL 100000
#define DIM    64
#define ALPHA  0.25f            // 1/(NUM_LAYERS+1)
#define NB     782               // coarse buckets of 128 nodes (dst >> 7)

// ---- workspace layout (u32 words) ----
constexpr size_t OFF_DIS    = 0;         // f32 [100096]
constexpr size_t OFF_ROWPTR = 100096;    // int [100001] (pad to 200192)
constexpr size_t OFF_BCNT   = 200192;    // int [NB]
constexpr size_t OFF_BBASE  = 201088;    // int [NB+1]
constexpr size_t OFF_GCUR   = 201984;    // int [NB]
constexpr size_t OFF_CW     = 202880;    // int2[1600000] = 3200000 words
constexpr size_t OFF_EMB16  = 3402880;   // half[6400000] = 3200000 words
constexpr size_t OFF_X1     = 6602880;   // half[6400000] (aliased by tmp during fill)
constexpr size_t OFF_X2     = 9802880;   // half[6400000]
constexpr size_t OFF_OUTF16 = 13002880;  // half[6400000]
constexpr size_t OFF_PART   = 16202880;  // f32 [2048]

// convert fp32 embedding -> fp16
__global__ void k_cvt(const float* __restrict__ emb, __half* __restrict__ emb16) {
    int i = blockIdx.x * blockDim.x + threadIdx.x;   // one float4 / thread
    if (i < (NNODES * DIM) / 4) {
        float4 v = ((const float4*)emb)[i];
        float2 bits;
        ((__half2*)&bits)[0] = __float22half2_rn(make_float2(v.x, v.y));
        ((__half2*)&bits)[1] = __float22half2_rn(make_float2(v.z, v.w));
        ((float2*)emb16)[i] = bits;
    }
}

// coarse bucket counts: per-block LDS hist, one global atomic per (block,bucket)
__global__ __launch_bounds__(256) void k_count(
    const int* __restrict__ ei, int* __restrict__ bcnt, int nblk) {
    __shared__ int hist[NB];
    int tid = threadIdx.x;
    int chunk = (NEDGES + nblk - 1) / nblk;
    int e0 = blockIdx.x * chunk;
    int e1 = min(e0 + chunk, NEDGES);
    for (int i = tid; i < NB; i += 256) hist[i] = 0;
    __syncthreads();
    for (int e = e0 + tid; e < e1; e += 256)
        atomicAdd(&hist[ei[NEDGES + e] >> 7], 1);
    __syncthreads();
    for (int b = tid; b < NB; b += 256)
        if (hist[b]) atomicAdd(&bcnt[b], hist[b]);
}

// exclusive scan of bucket counts -> bucket bases; init fill cursors
__global__ __launch_bounds__(1024) void k_bscan(
    const int* __restrict__ bcnt, int* __restrict__ bbase, int* __restrict__ gcur) {
    __shared__ int s[1024];
    int tid = threadIdx.x;
    int v = (tid < NB) ? bcnt[tid] : 0;
    s[tid] = v;
    __syncthreads();
    for (int off = 1; off < 1024; off <<= 1) {
        int t = s[tid];
        if (tid >= off) t += s[tid - off];
        __syncthreads();
        s[tid] = t;
        __syncthreads();
    }
    if (tid < NB) {
        int base = s[tid] - v;
        bbase[tid] = base;
        gcur[tid] = base;
    }
    if (tid == NB) bbase[NB] = NEDGES;
}

// fill pass 1: partition edges into NB coarse buckets (128 dst-nodes each)
__global__ __launch_bounds__(256) void k_fill1(
    const int* __restrict__ ei, int* __restrict__ gcursor,
    int2* __restrict__ tmp, int nblk) {
    __shared__ int hist[NB];
    __shared__ int base[NB];
    int tid = threadIdx.x;
    int chunk = (NEDGES + nblk - 1) / nblk;
    int e0 = blockIdx.x * chunk;
    int e1 = min(e0 + chunk, NEDGES);
    for (int i = tid; i < NB; i += 256) hist[i] = 0;
    __syncthreads();
    for (int e = e0 + tid; e < e1; e += 256)
        atomicAdd(&hist[ei[NEDGES + e] >> 7], 1);
    __syncthreads();
    for (int b = tid; b < NB; b += 256) {
        int c = hist[b];
        base[b] = c ? atomicAdd(&gcursor[b], c) : 0;
        hist[b] = 0;
    }
    __syncthreads();
    for (int e = e0 + tid; e < e1; e += 256) {
        int s = ei[e];
        int d = ei[NEDGES + e];
        int bk = d >> 7;
        int loc = atomicAdd(&hist[bk], 1);
        int2 v; v.x = s; v.y = d;
        tmp[base[bk] + loc] = v;
    }
}

// fill pass 2a: per bucket, per-node degree in LDS -> dis + rowptr (coalesced)
__global__ __launch_bounds__(256) void k_fill2a(
    const int* __restrict__ bbase, const int2* __restrict__ tmp,
    float* __restrict__ dis, int* __restrict__ rowptr) {
    __shared__ int dcnt[128];
    __shared__ int sc[128];
    int b = blockIdx.x;
    int tid = threadIdx.x;
    int n0 = b << 7;
    int s0 = bbase[b];
    int n = bbase[b + 1] - s0;
    if (tid < 128) dcnt[tid] = 0;
    __syncthreads();
    for (int i = tid; i < n; i += 256)
        atomicAdd(&dcnt[tmp[s0 + i].y & 127], 1);
    __syncthreads();
    int node = n0 + tid;
    if (tid < 128) {
        int d = dcnt[tid];
        if (node < NNODES) dis[node] = d ? rsqrtf((float)d) : 0.0f;
        sc[tid] = d;
    }
    __syncthreads();
    // exclusive scan of 128 degrees
    for (int off = 1; off < 128; off <<= 1) {
        int t = 0;
        if (tid < 128) {
            t = sc[tid];
            if (tid >= off) t += sc[tid - off];
        }
        __syncthreads();
        if (tid < 128) sc[tid] = t;
        __syncthreads();
    }
    if (tid < 128 && node < NNODES) rowptr[node] = s0 + sc[tid] - dcnt[tid];
    if (b == 0 && tid == 0) rowptr[NNODES] = NEDGES;
}

// fill pass 2b: per bucket, build CSR segment in LDS, attach weight, stream out
__global__ __launch_bounds__(256) void k_fill2b(
    const int* __restrict__ bbase, const int* __restrict__ rowptr,
    const float* __restrict__ dis, const int2* __restrict__ tmp,
    int2* __restrict__ cw) {
    __shared__ int2 seg[4096];
    __shared__ int cur[128];
    int b = blockIdx.x;
    int tid = threadIdx.x;
    int n0 = b << 7;
    int s0 = bbase[b];
    int n = bbase[b + 1] - s0;
    if (tid < 128) {
        int node = n0 + tid;
        cur[tid] = (node < NNODES) ? rowptr[node] - s0 : n;
    }
    __syncthreads();
    for (int i = tid; i < n; i += 256) {
        int2 e = tmp[s0 + i];
        int ln = e.y & 127;
        int p = atomicAdd(&cur[ln], 1);
        if (p < 4096) {
            int2 v; v.x = e.x; v.y = __float_as_int(dis[e.x]);
            seg[p] = v;
        }
    }
    __syncthreads();
    for (int i = tid; i < n; i += 256) cw[s0 + i] = seg[i];
}

// one wave per node; 4 edge-groups x 16 lanes; each lane owns 4 dims (8 B fp16).
// MODE 0/1: dst = x_next (fp16). MODE 2: dst = out = ALPHA*(emb+x1+x2+y) (fp16).
template <int MODE>
__global__ __launch_bounds__(256) void k_prop(
    const int* __restrict__ rowptr, const int2* __restrict__ cw,
    const float* __restrict__ dis, const __half* __restrict__ xin,
    __half* __restrict__ dst, const __half* __restrict__ emb16,
    const __half* __restrict__ x1, const __half* __restrict__ x2) {
    int gt = blockIdx.x * 256 + threadIdx.x;
    int node = gt >> 6;
    if (node >= NNODES) return;
    int lane = threadIdx.x & 63;
    int g = lane >> 4;     // edge group 0..3
    int c = lane & 15;     // 4-dim chunk within row
    int r0 = __builtin_amdgcn_readfirstlane(rowptr[node]);
    int r1 = __builtin_amdgcn_readfirstlane(rowptr[node + 1]);
    float4 acc0 = {0.f, 0.f, 0.f, 0.f}, acc1 = {0.f, 0.f, 0.f, 0.f};
    int j = r0 + g;
    for (; j + 4 < r1; j += 8) {           // 2 edges per group in flight
        int2 e0 = cw[j];
        int2 e1 = cw[j + 4];
        float2 r0v = *(const float2*)(xin + (size_t)e0.x * DIM + c * 4);
        float2 r1v = *(const float2*)(xin + (size_t)e1.x * DIM + c * 4);
        float w0 = __int_as_float(e0.y), w1 = __int_as_float(e1.y);
        float2 f0 = __half22float2(((__half2*)&r0v)[0]);
        float2 f1 = __half22float2(((__half2*)&r0v)[1]);
        float2 f2 = __half22float2(((__half2*)&r1v)[0]);
        float2 f3 = __half22float2(((__half2*)&r1v)[1]);
        acc0.x += w0 * f0.x; acc0.y += w0 * f0.y;
        acc0.z += w0 * f1.x; acc0.w += w0 * f1.y;
        acc1.x += w1 * f2.x; acc1.y += w1 * f2.y;
        acc1.z += w1 * f3.x; acc1.w += w1 * f3.y;
    }
    for (; j < r1; j += 4) {
        int2 e = cw[j];
        float2 rv = *(const float2*)(xin + (size_t)e.x * DIM + c * 4);
        float w = __int_as_float(e.y);
        float2 f0 = __half22float2(((__half2*)&rv)[0]);
        float2 f1 = __half22float2(((__half2*)&rv)[1]);
        acc0.x += w * f0.x; acc0.y += w * f0.y;
        acc0.z += w * f1.x; acc0.w += w * f1.y;
    }
    acc0.x += acc1.x; acc0.y += acc1.y; acc0.z += acc1.z; acc0.w += acc1.w;
    acc0.x += __shfl_xor(acc0.x, 16); acc0.y += __shfl_xor(acc0.y, 16);
    acc0.z += __shfl_xor(acc0.z, 16); acc0.w += __shfl_xor(acc0.w, 16);
    acc0.x += __shfl_xor(acc0.x, 32); acc0.y += __shfl_xor(acc0.y, 32);
    acc0.z += __shfl_xor(acc0.z, 32); acc0.w += __shfl_xor(acc0.w, 32);
    if (lane < 16) {
        float dn = dis[node];
        float yx = dn * acc0.x, yy = dn * acc0.y;
        float yz = dn * acc0.z, yw = dn * acc0.w;
        size_t idx = (size_t)node * DIM + c * 4;
        if (MODE == 2) {
            float2 eb = *(const float2*)(emb16 + idx);
            float2 ab = *(const float2*)(x1 + idx);
            float2 bb = *(const float2*)(x2 + idx);
            float2 e0 = __half22float2(((__half2*)&eb)[0]);
            float2 e1 = __half22float2(((__half2*)&eb)[1]);
            float2 a0 = __half22float2(((__half2*)&ab)[0]);
            float2 a1 = __half22float2(((__half2*)&ab)[1]);
            float2 b0 = __half22float2(((__half2*)&bb)[0]);
            float2 b1 = __half22float2(((__half2*)&bb)[1]);
            yx = ALPHA * (e0.x + a0.x + b0.x + yx);
            yy = ALPHA * (e0.y + a0.y + b0.y + yy);
            yz = ALPHA * (e1.x + a1.x + b1.x + yz);
            yw = ALPHA * (e1.y + a1.y + b1.y + yw);
        }
        float2 bits;
        ((__half2*)&bits)[0] = __float22half2_rn(make_float2(yx, yy));
        ((__half2*)&bits)[1] = __float22half2_rn(make_float2(yz, yw));
        *(float2*)(dst + idx) = bits;
    }
}

// LDS-tiled MLP GEMM over fp16 outf: 64 labels/block, xs k-major fp32 in LDS.
__global__ __launch_bounds__(256) void k_mlp(
    const __half* __restrict__ outf, const int* __restrict__ eli,
    const float* __restrict__ lbl, const float* __restrict__ W1,
    const float* __restrict__ b1, const float* __restrict__ W2,
    const float* __restrict__ b2, float* __restrict__ pred,
    float* __restrict__ partial) {
    __shared__ float xs[128][68];
    __shared__ float w1s[128 * 64];
    __shared__ float ws[4];
    int tid = threadIdx.x;
    int lb = blockIdx.x * 64;

    {
        const float4* src = (const float4*)W1;
        float4* dst = (float4*)w1s;
        for (int i = tid; i < 2048; i += 256) dst[i] = src[i];
    }
    {
        int lab = tid >> 2, q = tid & 3;
        int l = lb + lab;
        int li = (l < NLABEL) ? l : (NLABEL - 1);
        int s = eli[li];
        int t = eli[NLABEL + li];
        const __half* srow = outf + (size_t)s * DIM;
        const __half* trow = outf + (size_t)t * DIM;
#pragma unroll
        for (int i = 0; i < 4; ++i) {
            int cc = q + 4 * i;           // 16B chunk 0..15 of the 256B concat row
            const __half* row = (cc < 8) ? srow + cc * 8 : trow + (cc - 8) * 8;
            float4 raw = *(const float4*)row;   // 8 halfs
            __half2* hp = (__half2*)&raw;
            int k = 8 * cc;
            float2 f;
            f = __half22float2(hp[0]); xs[k + 0][lab] = f.x; xs[k + 1][lab] = f.y;
            f = __half22float2(hp[1]); xs[k + 2][lab] = f.x; xs[k + 3][lab] = f.y;
            f = __half22float2(hp[2]); xs[k + 4][lab] = f.x; xs[k + 5][lab] = f.y;
            f = __half22float2(hp[3]); xs[k + 6][lab] = f.x; xs[k + 7][lab] = f.y;
        }
    }
    __syncthreads();

    int jcol = tid & 15;
    int lrow = tid >> 4;
    float acc[4][4];
#pragma unroll
    for (int a = 0; a < 4; ++a)
#pragma unroll
        for (int b = 0; b < 4; ++b) acc[a][b] = 0.f;

#pragma unroll 4
    for (int k = 0; k < 128; ++k) {
        float4 xv = *(const float4*)(&xs[k][4 * lrow]);
        float4 wv = *(const float4*)(&w1s[k * 64 + 4 * jcol]);
        acc[0][0] += xv.x * wv.x; acc[0][1] += xv.x * wv.y;
        acc[0][2] += xv.x * wv.z; acc[0][3] += xv.x * wv.w;
        acc[1][0] += xv.y * wv.x; acc[1][1] += xv.y * wv.y;
        acc[1][2] += xv.y * wv.z; acc[1][3] += xv.y * wv.w;
        acc[2][0] += xv.z * wv.x; acc[2][1] += xv.z * wv.y;
        acc[2][2] += xv.z * wv.z; acc[2][3] += xv.z * wv.w;
        acc[3][0] += xv.w * wv.x; acc[3][1] += xv.w * wv.y;
        acc[3][2] += xv.w * wv.z; acc[3][3] += xv.w * wv.w;
    }

    float4 b1v = *(const float4*)(b1 + 4 * jcol);
    float4 w2v = *(const float4*)(W2 + 4 * jcol);
    float p[4];
#pragma unroll
    for (int a = 0; a < 4; ++a) {
        p[a] = fmaxf(acc[a][0] + b1v.x, 0.f) * w2v.x
             + fmaxf(acc[a][1] + b1v.y, 0.f) * w2v.y
             + fmaxf(acc[a][2] + b1v.z, 0.f) * w2v.z
             + fmaxf(acc[a][3] + b1v.w, 0.f) * w2v.w;
    }
#pragma unroll
    for (int off = 1; off <= 8; off <<= 1) {
#pragma unroll
        for (int a = 0; a < 4; ++a) p[a] += __shfl_xor(p[a], off);
    }
    float lsum = 0.f;
    if (jcol == 0) {
        float b2v = b2[0];
#pragma unroll
        for (int a = 0; a < 4; ++a) {
            int l = lb + 4 * lrow + a;
            if (l < NLABEL) {
                float predv = p[a] + b2v;
                pred[l] = predv;
                float d = predv - lbl[l];
                lsum += d * d;
            }
        }
    }
    lsum += __shfl_xor(lsum, 16);
    lsum += __shfl_xor(lsum, 32);
    if ((tid & 63) == 0) ws[tid >> 6] = lsum;
    __syncthreads();
    if (tid == 0) partial[blockIdx.x] = (ws[0] + ws[1]) + (ws[2] + ws[3]);
}

__global__ void k_loss(const float* __restrict__ partial, float* __restrict__ lossout,
                       int n) {
    __shared__ float s[512];
    int tid = threadIdx.x;
    float v = 0.f;
    for (int i = tid; i < n; i += 512) v += partial[i];
    s[tid] = v;
    __syncthreads();
    for (int off = 256; off >= 1; off >>= 1) {
        if (tid < off) s[tid] += s[tid + off];
        __syncthreads();
    }
    if (tid == 0) lossout[0] = s[0] / (float)NLABEL;
}

extern "C" void kernel_launch(void* const* d_in, const int* in_sizes, int n_in,
                              void* d_out, int out_size, void* d_ws, size_t ws_size,
                              hipStream_t stream) {
    const int*   ei  = (const int*)d_in[0];
    const int*   eli = (const int*)d_in[1];
    const float* lbl = (const float*)d_in[2];
    const float* emb = (const float*)d_in[3];
    const float* W1  = (const float*)d_in[4];
    const float* b1  = (const float*)d_in[5];
    const float* W2  = (const float*)d_in[6];
    const float* b2  = (const float*)d_in[7];
    float* outp = (float*)d_out;               // pred[100000] ++ loss[1]

    char* wsb = (char*)d_ws;
    float*  dis    = (float*)wsb + OFF_DIS;
    int*    rowptr = (int*)wsb + OFF_ROWPTR;
    int*    bcnt   = (int*)wsb + OFF_BCNT;
    int*    bbase  = (int*)wsb + OFF_BBASE;
    int*    gcur   = (int*)wsb + OFF_GCUR;
    int2*   cw     = (int2*)((int*)wsb + OFF_CW);
    __half* emb16  = (__half*)((int*)wsb + OFF_EMB16);
    __half* x1     = (__half*)((int*)wsb + OFF_X1);
    __half* x2     = (__half*)((int*)wsb + OFF_X2);
    __half* outf   = (__half*)((int*)wsb + OFF_OUTF16);
    float*  part   = (float*)wsb + OFF_PART;
    int2*   tmp    = (int2*)x1;                // alias: free until k_prop<0>

    const int T = 256;
    hipMemsetAsync(bcnt, 0, NB * sizeof(int), stream);
    hipLaunchKernelGGL(k_cvt, dim3((NNODES * DIM / 4 + T - 1) / T), dim3(T), 0, stream, emb, emb16);
    const int NBLK1 = 128;
    hipLaunchKernelGGL(k_count, dim3(NBLK1), dim3(T), 0, stream, ei, bcnt, NBLK1);
    hipLaunchKernelGGL(k_bscan, dim3(1), dim3(1024), 0, stream, bcnt, bbase, gcur);
    hipLaunchKernelGGL(k_fill1, dim3(NBLK1), dim3(T), 0, stream, ei, gcur, tmp, NBLK1);
    hipLaunchKernelGGL(k_fill2a, dim3(NB), dim3(T), 0, stream, bbase, tmp, dis, rowptr);
    hipLaunchKernelGGL(k_fill2b, dim3(NB), dim3(T), 0, stream, bbase, rowptr, dis, tmp, cw);

    // x1 = P(emb); x2 = P(x1); outf = ALPHA*(emb + x1 + x2 + P(x2))   [all fp16]
    dim3 pgrid((NNODES * 64) / T);
    hipLaunchKernelGGL((k_prop<0>), pgrid, dim3(T), 0, stream, rowptr, cw, dis, emb16, x1,   nullptr, nullptr, nullptr);
    hipLaunchKernelGGL((k_prop<1>), pgrid, dim3(T), 0, stream, rowptr, cw, dis, x1,    x2,   nullptr, nullptr, nullptr);
    hipLaunchKernelGGL((k_prop<2>), pgrid, dim3(T), 0, stream, rowptr, cw, dis, x2,    outf, emb16, x1, x2);

    const int MLPB = (NLABEL + 63) / 64;   // 1563
    hipLaunchKernelGGL(k_mlp, dim3(MLPB), dim3(T), 0, stream, outf, eli, lbl, W1, b1, W2, b2, outp, part);
    hipLaunchKernelGGL(k_loss, dim3(1), dim3(512), 0, stream, part, outp + NLABEL, MLPB);
}

// Round 7
// 241.773 us; speedup vs baseline: 2.5489x; 1.1045x over previous
//
#include <hip/hip_runtime.h>
#include <hip/hip_fp16.h>
#include <math.h>

// ---- problem constants (match reference) ----
#define NNODES 100000
#define NEDGES 1600000
#define NLABEL 100000
#define DIM    64
#define ALPHA  0.25f            // 1/(NUM_LAYERS+1)
#define NB     782               // coarse buckets of 128 nodes (dst >> 7)
#define NBLKF  256               // blocks for count/fill1 (1024 threads each)

// ---- workspace layout (u32 words) ----
constexpr size_t OFF_DIS    = 0;         // f32 [100096]
constexpr size_t OFF_ROWPTR = 100096;    // int [100001] (pad to 200192)
constexpr size_t OFF_BCNT   = 200192;    // int [NB]
constexpr size_t OFF_BBASE  = 201088;    // int [NB+1]
constexpr size_t OFF_GCUR   = 201984;    // int [NB]
constexpr size_t OFF_CW     = 202880;    // int2[1600000] = 3200000 words
constexpr size_t OFF_EMB16  = 3402880;   // half[6400000] = 3200000 words
constexpr size_t OFF_X1     = 6602880;   // half[6400000] (aliased by tmp during fill)
constexpr size_t OFF_X2     = 9802880;   // half[6400000]
constexpr size_t OFF_OUTF16 = 13002880;  // half[6400000]
constexpr size_t OFF_PART   = 16202880;  // f32 [2048]

// convert fp32 embedding -> fp16
__global__ void k_cvt(const float* __restrict__ emb, __half* __restrict__ emb16) {
    int i = blockIdx.x * blockDim.x + threadIdx.x;   // one float4 / thread
    if (i < (NNODES * DIM) / 4) {
        float4 v = ((const float4*)emb)[i];
        float2 bits;
        ((__half2*)&bits)[0] = __float22half2_rn(make_float2(v.x, v.y));
        ((__half2*)&bits)[1] = __float22half2_rn(make_float2(v.z, v.w));
        ((float2*)emb16)[i] = bits;
    }
}

// coarse bucket counts: per-block LDS hist, one global atomic per (block,bucket)
__global__ __launch_bounds__(1024) void k_count(
    const int* __restrict__ ei, int* __restrict__ bcnt) {
    __shared__ int hist[NB];
    int tid = threadIdx.x;
    const int chunk = (((NEDGES + NBLKF - 1) / NBLKF) + 3) & ~3;   // 6252 (x4)
    int e0 = blockIdx.x * chunk;
    int e1 = min(e0 + chunk, NEDGES);
    for (int i = tid; i < NB; i += 1024) hist[i] = 0;
    __syncthreads();
    const int* dsts = ei + NEDGES;
    for (int e = e0 + tid * 4; e + 3 < e1; e += 4096) {
        int4 d = *(const int4*)(dsts + e);
        atomicAdd(&hist[d.x >> 7], 1);
        atomicAdd(&hist[d.y >> 7], 1);
        atomicAdd(&hist[d.z >> 7], 1);
        atomicAdd(&hist[d.w >> 7], 1);
    }
    __syncthreads();
    for (int b = tid; b < NB; b += 1024)
        if (hist[b]) atomicAdd(&bcnt[b], hist[b]);
}

// exclusive scan of bucket counts -> bucket bases; init fill cursors
__global__ __launch_bounds__(1024) void k_bscan(
    const int* __restrict__ bcnt, int* __restrict__ bbase, int* __restrict__ gcur) {
    __shared__ int s[1024];
    int tid = threadIdx.x;
    int v = (tid < NB) ? bcnt[tid] : 0;
    s[tid] = v;
    __syncthreads();
    for (int off = 1; off < 1024; off <<= 1) {
        int t = s[tid];
        if (tid >= off) t += s[tid - off];
        __syncthreads();
        s[tid] = t;
        __syncthreads();
    }
    if (tid < NB) {
        int base = s[tid] - v;
        bbase[tid] = base;
        gcur[tid] = base;
    }
    if (tid == NB) bbase[NB] = NEDGES;
}

// fill pass 1: partition edges into NB coarse buckets (128 dst-nodes each)
__global__ __launch_bounds__(1024) void k_fill1(
    const int* __restrict__ ei, int* __restrict__ gcursor,
    int2* __restrict__ tmp) {
    __shared__ int hist[NB];
    __shared__ int base[NB];
    int tid = threadIdx.x;
    const int chunk = (((NEDGES + NBLKF - 1) / NBLKF) + 3) & ~3;   // 6252 (x4)
    int e0 = blockIdx.x * chunk;
    int e1 = min(e0 + chunk, NEDGES);
    for (int i = tid; i < NB; i += 1024) hist[i] = 0;
    __syncthreads();
    const int* srcs = ei;
    const int* dsts = ei + NEDGES;
    for (int e = e0 + tid * 4; e + 3 < e1; e += 4096) {
        int4 d = *(const int4*)(dsts + e);
        atomicAdd(&hist[d.x >> 7], 1);
        atomicAdd(&hist[d.y >> 7], 1);
        atomicAdd(&hist[d.z >> 7], 1);
        atomicAdd(&hist[d.w >> 7], 1);
    }
    __syncthreads();
    for (int b = tid; b < NB; b += 1024) {
        int c = hist[b];
        base[b] = c ? atomicAdd(&gcursor[b], c) : 0;
        hist[b] = 0;
    }
    __syncthreads();
    for (int e = e0 + tid * 4; e + 3 < e1; e += 4096) {
        int4 s = *(const int4*)(srcs + e);
        int4 d = *(const int4*)(dsts + e);
        int b0 = d.x >> 7, b1 = d.y >> 7, b2 = d.z >> 7, b3 = d.w >> 7;
        int l0 = atomicAdd(&hist[b0], 1);
        int l1 = atomicAdd(&hist[b1], 1);
        int l2 = atomicAdd(&hist[b2], 1);
        int l3 = atomicAdd(&hist[b3], 1);
        int2 v;
        v.x = s.x; v.y = d.x; tmp[base[b0] + l0] = v;
        v.x = s.y; v.y = d.y; tmp[base[b1] + l1] = v;
        v.x = s.z; v.y = d.z; tmp[base[b2] + l2] = v;
        v.x = s.w; v.y = d.w; tmp[base[b3] + l3] = v;
    }
}

// fill pass 2a: per bucket, per-node degree in LDS -> dis + rowptr (coalesced)
__global__ __launch_bounds__(256) void k_fill2a(
    const int* __restrict__ bbase, const int2* __restrict__ tmp,
    float* __restrict__ dis, int* __restrict__ rowptr) {
    __shared__ int dcnt[128];
    __shared__ int sc[128];
    int b = blockIdx.x;
    int tid = threadIdx.x;
    int n0 = b << 7;
    int s0 = bbase[b];
    int n = bbase[b + 1] - s0;
    if (tid < 128) dcnt[tid] = 0;
    __syncthreads();
    for (int i = tid; i < n; i += 256)
        atomicAdd(&dcnt[tmp[s0 + i].y & 127], 1);
    __syncthreads();
    int node = n0 + tid;
    if (tid < 128) {
        int d = dcnt[tid];
        if (node < NNODES) dis[node] = d ? rsqrtf((float)d) : 0.0f;
        sc[tid] = d;
    }
    __syncthreads();
    for (int off = 1; off < 128; off <<= 1) {
        int t = 0;
        if (tid < 128) {
            t = sc[tid];
            if (tid >= off) t += sc[tid - off];
        }
        __syncthreads();
        if (tid < 128) sc[tid] = t;
        __syncthreads();
    }
    if (tid < 128 && node < NNODES) rowptr[node] = s0 + sc[tid] - dcnt[tid];
    if (b == 0 && tid == 0) rowptr[NNODES] = NEDGES;
}

// fill pass 2b: per bucket, build CSR segment in LDS, attach weight, stream out
__global__ __launch_bounds__(256) void k_fill2b(
    const int* __restrict__ bbase, const int* __restrict__ rowptr,
    const float* __restrict__ dis, const int2* __restrict__ tmp,
    int2* __restrict__ cw) {
    __shared__ int2 seg[4096];
    __shared__ int cur[128];
    int b = blockIdx.x;
    int tid = threadIdx.x;
    int n0 = b << 7;
    int s0 = bbase[b];
    int n = bbase[b + 1] - s0;
    if (tid < 128) {
        int node = n0 + tid;
        cur[tid] = (node < NNODES) ? rowptr[node] - s0 : n;
    }
    __syncthreads();
    for (int i = tid; i < n; i += 256) {
        int2 e = tmp[s0 + i];
        int ln = e.y & 127;
        int p = atomicAdd(&cur[ln], 1);
        if (p < 4096) {
            int2 v; v.x = e.x; v.y = __float_as_int(dis[e.x]);
            seg[p] = v;
        }
    }
    __syncthreads();
    for (int i = tid; i < n; i += 256) cw[s0 + i] = seg[i];
}

// one wave per node; 4 edge-groups x 16 lanes; each lane owns 4 dims (8 B fp16).
// 4-deep edge pipeline per group. MODE 0/1: dst = x_next. MODE 2: fused out.
template <int MODE>
__global__ __launch_bounds__(256) void k_prop(
    const int* __restrict__ rowptr, const int2* __restrict__ cw,
    const float* __restrict__ dis, const __half* __restrict__ xin,
    __half* __restrict__ dst, const __half* __restrict__ emb16,
    const __half* __restrict__ x1, const __half* __restrict__ x2) {
    int gt = blockIdx.x * 256 + threadIdx.x;
    int node = gt >> 6;
    if (node >= NNODES) return;
    int lane = threadIdx.x & 63;
    int g = lane >> 4;     // edge group 0..3
    int c = lane & 15;     // 4-dim chunk within row
    int r0 = __builtin_amdgcn_readfirstlane(rowptr[node]);
    int r1 = __builtin_amdgcn_readfirstlane(rowptr[node + 1]);
    float4 acc0 = {0.f, 0.f, 0.f, 0.f}, acc1 = {0.f, 0.f, 0.f, 0.f};
    float4 acc2 = {0.f, 0.f, 0.f, 0.f}, acc3 = {0.f, 0.f, 0.f, 0.f};
    int j = r0 + g;
    for (; j + 12 < r1; j += 16) {         // 4 edges per group in flight
        int2 e0 = cw[j];
        int2 e1 = cw[j + 4];
        int2 e2 = cw[j + 8];
        int2 e3 = cw[j + 12];
        float2 r0v = *(const float2*)(xin + (size_t)e0.x * DIM + c * 4);
        float2 r1v = *(const float2*)(xin + (size_t)e1.x * DIM + c * 4);
        float2 r2v = *(const float2*)(xin + (size_t)e2.x * DIM + c * 4);
        float2 r3v = *(const float2*)(xin + (size_t)e3.x * DIM + c * 4);
        float w0 = __int_as_float(e0.y), w1 = __int_as_float(e1.y);
        float w2 = __int_as_float(e2.y), w3 = __int_as_float(e3.y);
        float2 f0a = __half22float2(((__half2*)&r0v)[0]);
        float2 f0b = __half22float2(((__half2*)&r0v)[1]);
        float2 f1a = __half22float2(((__half2*)&r1v)[0]);
        float2 f1b = __half22float2(((__half2*)&r1v)[1]);
        float2 f2a = __half22float2(((__half2*)&r2v)[0]);
        float2 f2b = __half22float2(((__half2*)&r2v)[1]);
        float2 f3a = __half22float2(((__half2*)&r3v)[0]);
        float2 f3b = __half22float2(((__half2*)&r3v)[1]);
        acc0.x += w0 * f0a.x; acc0.y += w0 * f0a.y;
        acc0.z += w0 * f0b.x; acc0.w += w0 * f0b.y;
        acc1.x += w1 * f1a.x; acc1.y += w1 * f1a.y;
        acc1.z += w1 * f1b.x; acc1.w += w1 * f1b.y;
        acc2.x += w2 * f2a.x; acc2.y += w2 * f2a.y;
        acc2.z += w2 * f2b.x; acc2.w += w2 * f2b.y;
        acc3.x += w3 * f3a.x; acc3.y += w3 * f3a.y;
        acc3.z += w3 * f3b.x; acc3.w += w3 * f3b.y;
    }
    for (; j + 4 < r1; j += 8) {           // 2 edges
        int2 e0 = cw[j];
        int2 e1 = cw[j + 4];
        float2 r0v = *(const float2*)(xin + (size_t)e0.x * DIM + c * 4);
        float2 r1v = *(const float2*)(xin + (size_t)e1.x * DIM + c * 4);
        float w0 = __int_as_float(e0.y), w1 = __int_as_float(e1.y);
        float2 f0a = __half22float2(((__half2*)&r0v)[0]);
        float2 f0b = __half22float2(((__half2*)&r0v)[1]);
        float2 f1a = __half22float2(((__half2*)&r1v)[0]);
        float2 f1b = __half22float2(((__half2*)&r1v)[1]);
        acc0.x += w0 * f0a.x; acc0.y += w0 * f0a.y;
        acc0.z += w0 * f0b.x; acc0.w += w0 * f0b.y;
        acc1.x += w1 * f1a.x; acc1.y += w1 * f1a.y;
        acc1.z += w1 * f1b.x; acc1.w += w1 * f1b.y;
    }
    for (; j < r1; j += 4) {               // 1 edge
        int2 e = cw[j];
        float2 rv = *(const float2*)(xin + (size_t)e.x * DIM + c * 4);
        float w = __int_as_float(e.y);
        float2 f0 = __half22float2(((__half2*)&rv)[0]);
        float2 f1 = __half22float2(((__half2*)&rv)[1]);
        acc0.x += w * f0.x; acc0.y += w * f0.y;
        acc0.z += w * f1.x; acc0.w += w * f1.y;
    }
    acc0.x += acc1.x; acc0.y += acc1.y; acc0.z += acc1.z; acc0.w += acc1.w;
    acc2.x += acc3.x; acc2.y += acc3.y; acc2.z += acc3.z; acc2.w += acc3.w;
    acc0.x += acc2.x; acc0.y += acc2.y; acc0.z += acc2.z; acc0.w += acc2.w;
    acc0.x += __shfl_xor(acc0.x, 16); acc0.y += __shfl_xor(acc0.y, 16);
    acc0.z += __shfl_xor(acc0.z, 16); acc0.w += __shfl_xor(acc0.w, 16);
    acc0.x += __shfl_xor(acc0.x, 32); acc0.y += __shfl_xor(acc0.y, 32);
    acc0.z += __shfl_xor(acc0.z, 32); acc0.w += __shfl_xor(acc0.w, 32);
    if (lane < 16) {
        float dn = dis[node];
        float yx = dn * acc0.x, yy = dn * acc0.y;
        float yz = dn * acc0.z, yw = dn * acc0.w;
        size_t idx = (size_t)node * DIM + c * 4;
        if (MODE == 2) {
            float2 eb = *(const float2*)(emb16 + idx);
            float2 ab = *(const float2*)(x1 + idx);
            float2 bb = *(const float2*)(x2 + idx);
            float2 e0 = __half22float2(((__half2*)&eb)[0]);
            float2 e1 = __half22float2(((__half2*)&eb)[1]);
            float2 a0 = __half22float2(((__half2*)&ab)[0]);
            float2 a1 = __half22float2(((__half2*)&ab)[1]);
            float2 b0 = __half22float2(((__half2*)&bb)[0]);
            float2 b1 = __half22float2(((__half2*)&bb)[1]);
            yx = ALPHA * (e0.x + a0.x + b0.x + yx);
            yy = ALPHA * (e0.y + a0.y + b0.y + yy);
            yz = ALPHA * (e1.x + a1.x + b1.x + yz);
            yw = ALPHA * (e1.y + a1.y + b1.y + yw);
        }
        float2 bits;
        ((__half2*)&bits)[0] = __float22half2_rn(make_float2(yx, yy));
        ((__half2*)&bits)[1] = __float22half2_rn(make_float2(yz, yw));
        *(float2*)(dst + idx) = bits;
    }
}

// LDS-tiled MLP GEMM over fp16 outf: 64 labels/block, xs k-major fp32 in LDS.
__global__ __launch_bounds__(256) void k_mlp(
    const __half* __restrict__ outf, const int* __restrict__ eli,
    const float* __restrict__ lbl, const float* __restrict__ W1,
    const float* __restrict__ b1, const float* __restrict__ W2,
    const float* __restrict__ b2, float* __restrict__ pred,
    float* __restrict__ partial) {
    __shared__ float xs[128][68];
    __shared__ float w1s[128 * 64];
    __shared__ float ws[4];
    int tid = threadIdx.x;
    int lb = blockIdx.x * 64;

    {
        const float4* src = (const float4*)W1;
        float4* dst = (float4*)w1s;
        for (int i = tid; i < 2048; i += 256) dst[i] = src[i];
    }
    {
        int lab = tid >> 2, q = tid & 3;
        int l = lb + lab;
        int li = (l < NLABEL) ? l : (NLABEL - 1);
        int s = eli[li];
        int t = eli[NLABEL + li];
        const __half* srow = outf + (size_t)s * DIM;
        const __half* trow = outf + (size_t)t * DIM;
#pragma unroll
        for (int i = 0; i < 4; ++i) {
            int cc = q + 4 * i;           // 16B chunk 0..15 of the 256B concat row
            const __half* row = (cc < 8) ? srow + cc * 8 : trow + (cc - 8) * 8;
            float4 raw = *(const float4*)row;   // 8 halfs
            __half2* hp = (__half2*)&raw;
            int k = 8 * cc;
            float2 f;
            f = __half22float2(hp[0]); xs[k + 0][lab] = f.x; xs[k + 1][lab] = f.y;
            f = __half22float2(hp[1]); xs[k + 2][lab] = f.x; xs[k + 3][lab] = f.y;
            f = __half22float2(hp[2]); xs[k + 4][lab] = f.x; xs[k + 5][lab] = f.y;
            f = __half22float2(hp[3]); xs[k + 6][lab] = f.x; xs[k + 7][lab] = f.y;
        }
    }
    __syncthreads();

    int jcol = tid & 15;
    int lrow = tid >> 4;
    float acc[4][4];
#pragma unroll
    for (int a = 0; a < 4; ++a)
#pragma unroll
        for (int b = 0; b < 4; ++b) acc[a][b] = 0.f;

#pragma unroll 4
    for (int k = 0; k < 128; ++k) {
        float4 xv = *(const float4*)(&xs[k][4 * lrow]);
        float4 wv = *(const float4*)(&w1s[k * 64 + 4 * jcol]);
        acc[0][0] += xv.x * wv.x; acc[0][1] += xv.x * wv.y;
        acc[0][2] += xv.x * wv.z; acc[0][3] += xv.x * wv.w;
        acc[1][0] += xv.y * wv.x; acc[1][1] += xv.y * wv.y;
        acc[1][2] += xv.y * wv.z; acc[1][3] += xv.y * wv.w;
        acc[2][0] += xv.z * wv.x; acc[2][1] += xv.z * wv.y;
        acc[2][2] += xv.z * wv.z; acc[2][3] += xv.z * wv.w;
        acc[3][0] += xv.w * wv.x; acc[3][1] += xv.w * wv.y;
        acc[3][2] += xv.w * wv.z; acc[3][3] += xv.w * wv.w;
    }

    float4 b1v = *(const float4*)(b1 + 4 * jcol);
    float4 w2v = *(const float4*)(W2 + 4 * jcol);
    float p[4];
#pragma unroll
    for (int a = 0; a < 4; ++a) {
        p[a] = fmaxf(acc[a][0] + b1v.x, 0.f) * w2v.x
             + fmaxf(acc[a][1] + b1v.y, 0.f) * w2v.y
             + fmaxf(acc[a][2] + b1v.z, 0.f) * w2v.z
             + fmaxf(acc[a][3] + b1v.w, 0.f) * w2v.w;
    }
#pragma unroll
    for (int off = 1; off <= 8; off <<= 1) {
#pragma unroll
        for (int a = 0; a < 4; ++a) p[a] += __shfl_xor(p[a], off);
    }
    float lsum = 0.f;
    if (jcol == 0) {
        float b2v = b2[0];
#pragma unroll
        for (int a = 0; a < 4; ++a) {
            int l = lb + 4 * lrow + a;
            if (l < NLABEL) {
                float predv = p[a] + b2v;
                pred[l] = predv;
                float d = predv - lbl[l];
                lsum += d * d;
            }
        }
    }
    lsum += __shfl_xor(lsum, 16);
    lsum += __shfl_xor(lsum, 32);
    if ((tid & 63) == 0) ws[tid >> 6] = lsum;
    __syncthreads();
    if (tid == 0) partial[blockIdx.x] = (ws[0] + ws[1]) + (ws[2] + ws[3]);
}

__global__ void k_loss(const float* __restrict__ partial, float* __restrict__ lossout,
                       int n) {
    __shared__ float s[512];
    int tid = threadIdx.x;
    float v = 0.f;
    for (int i = tid; i < n; i += 512) v += partial[i];
    s[tid] = v;
    __syncthreads();
    for (int off = 256; off >= 1; off >>= 1) {
        if (tid < off) s[tid] += s[tid + off];
        __syncthreads();
    }
    if (tid == 0) lossout[0] = s[0] / (float)NLABEL;
}

extern "C" void kernel_launch(void* const* d_in, const int* in_sizes, int n_in,
                              void* d_out, int out_size, void* d_ws, size_t ws_size,
                              hipStream_t stream) {
    const int*   ei  = (const int*)d_in[0];
    const int*   eli = (const int*)d_in[1];
    const float* lbl = (const float*)d_in[2];
    const float* emb = (const float*)d_in[3];
    const float* W1  = (const float*)d_in[4];
    const float* b1  = (const float*)d_in[5];
    const float* W2  = (const float*)d_in[6];
    const float* b2  = (const float*)d_in[7];
    float* outp = (float*)d_out;               // pred[100000] ++ loss[1]

    char* wsb = (char*)d_ws;
    float*  dis    = (float*)wsb + OFF_DIS;
    int*    rowptr = (int*)wsb + OFF_ROWPTR;
    int*    bcnt   = (int*)wsb + OFF_BCNT;
    int*    bbase  = (int*)wsb + OFF_BBASE;
    int*    gcur   = (int*)wsb + OFF_GCUR;
    int2*   cw     = (int2*)((int*)wsb + OFF_CW);
    __half* emb16  = (__half*)((int*)wsb + OFF_EMB16);
    __half* x1     = (__half*)((int*)wsb + OFF_X1);
    __half* x2     = (__half*)((int*)wsb + OFF_X2);
    __half* outf   = (__half*)((int*)wsb + OFF_OUTF16);
    float*  part   = (float*)wsb + OFF_PART;
    int2*   tmp    = (int2*)x1;                // alias: free until k_prop<0>

    const int T = 256;
    hipMemsetAsync(bcnt, 0, NB * sizeof(int), stream);
    hipLaunchKernelGGL(k_cvt, dim3((NNODES * DIM / 4 + T - 1) / T), dim3(T), 0, stream, emb, emb16);
    hipLaunchKernelGGL(k_count, dim3(NBLKF), dim3(1024), 0, stream, ei, bcnt);
    hipLaunchKernelGGL(k_bscan, dim3(1), dim3(1024), 0, stream, bcnt, bbase, gcur);
    hipLaunchKernelGGL(k_fill1, dim3(NBLKF), dim3(1024), 0, stream, ei, gcur, tmp);
    hipLaunchKernelGGL(k_fill2a, dim3(NB), dim3(T), 0, stream, bbase, tmp, dis, rowptr);
    hipLaunchKernelGGL(k_fill2b, dim3(NB), dim3(T), 0, stream, bbase, rowptr, dis, tmp, cw);

    // x1 = P(emb); x2 = P(x1); outf = ALPHA*(emb + x1 + x2 + P(x2))   [all fp16]
    dim3 pgrid((NNODES * 64) / T);
    hipLaunchKernelGGL((k_prop<0>), pgrid, dim3(T), 0, stream, rowptr, cw, dis, emb16, x1,   nullptr, nullptr, nullptr);
    hipLaunchKernelGGL((k_prop<1>), pgrid, dim3(T), 0, stream, rowptr, cw, dis, x1,    x2,   nullptr, nullptr, nullptr);
    hipLaunchKernelGGL((k_prop<2>), pgrid, dim3(T), 0, stream, rowptr, cw, dis, x2,    outf, emb16, x1, x2);

    const int MLPB = (NLABEL + 63) / 64;   // 1563
    hipLaunchKernelGGL(k_mlp, dim3(MLPB), dim3(T), 0, stream, outf, eli, lbl, W1, b1, W2, b2, outp, part);
    hipLaunchKernelGGL(k_loss, dim3(1), dim3(512), 0, stream, part, outp + NLABEL, MLPB);
}